// Round 12
// baseline (444.164 us; speedup 1.0000x reference)
//
#include <hip/hip_runtime.h>
#include <hip/hip_bf16.h>
#include <math.h>

#define N_PTS 16384
#define NUM_G 64
#define GRP_K 32
#define EPSF 1e-5f

typedef short bf16x8 __attribute__((ext_vector_type(8)));
typedef short bf16x4 __attribute__((ext_vector_type(4)));
typedef float f32x4 __attribute__((ext_vector_type(4)));
typedef unsigned short u16x8 __attribute__((ext_vector_type(8)));

__device__ __forceinline__ unsigned short f2bf(float x) {
    unsigned int u = __builtin_bit_cast(unsigned int, x);
    u = (u + 0x7FFFu + ((u >> 16) & 1u)) >> 16;
    return (unsigned short)u;
}
__device__ __forceinline__ float bf2f(unsigned short h) {
    unsigned int u = ((unsigned int)h) << 16;
    return __builtin_bit_cast(float, u);
}

// ---------------- Phase A: FPS v4 — float2 LDS (halve the LDS issue count) ----------------
// R11 showed 32x ds_read_b32/thread/iter == the old global-remat cost. The knob is
// issue COUNT: pack (x,y) as float2 -> 16x ds_read_b64 (same bytes, 2-way-free banks).
// dist[16]+z[16] stay in registers (fits in the measured 52-VGPR allocation).
__global__ __launch_bounds__(1024)
__attribute__((amdgpu_waves_per_eu(4, 4)))
void fps_kernel(const float* __restrict__ pcd, int* __restrict__ cidx) {
    const int b = blockIdx.x;
    const int tid = threadIdx.x;
    const int lane = tid & 63, w = tid >> 6;
    const float* xb = pcd + (size_t)b * 6 * N_PTS;

    __shared__ float2 lxy[N_PTS];               // 131,072 B
    __shared__ unsigned long long wk[2][16];
    __shared__ int clds[NUM_G];

    float dist[16], pzr[16];
#pragma unroll
    for (int j = 0; j < 16; ++j) {
        int p = tid + 1024 * j;
        float xv = xb[p];
        float yv = xb[N_PTS + p];
        lxy[p] = make_float2(xv, yv);
        pzr[j] = xb[2 * N_PTS + p];
        dist[j] = 1e10f;
    }
    __syncthreads();

    int far = 0;
    for (int it = 0; it < NUM_G; ++it) {
        int fu = __builtin_amdgcn_readfirstlane(far);
        float2 cxy = lxy[fu];
        float cz = xb[2 * N_PTS + fu];
        if (tid == 0) clds[it] = fu;

        float bv = -1.0f;
        int bj = 0;
#pragma unroll
        for (int j = 0; j < 16; ++j) {
            float2 q = lxy[tid + 1024 * j];
            float dx = __fsub_rn(q.x, cxy.x);
            float dy = __fsub_rn(q.y, cxy.y);
            float dz = __fsub_rn(pzr[j], cz);
            float d = __fadd_rn(__fadd_rn(__fmul_rn(dx, dx), __fmul_rn(dy, dy)),
                                __fmul_rn(dz, dz));
            dist[j] = fminf(dist[j], d);
            if (dist[j] > bv) { bv = dist[j]; bj = j; }  // j asc => lowest idx on tie
        }
        unsigned long long kmax =
            ((unsigned long long)__float_as_uint(bv) << 32) |
            (unsigned int)~(tid + 1024 * bj);
#pragma unroll
        for (int m = 1; m < 64; m <<= 1) {
            unsigned long long o = __shfl_xor(kmax, m, 64);
            kmax = o > kmax ? o : kmax;
        }
        if (lane == 0) wk[it & 1][w] = kmax;
        __syncthreads();
        unsigned long long k2 = (lane < 16) ? wk[it & 1][lane] : 0ull;
#pragma unroll
        for (int m = 1; m < 16; m <<= 1) {
            unsigned long long o = __shfl_xor(k2, m, 64);
            k2 = o > k2 ? o : k2;
        }
        k2 = __shfl(k2, 0, 64);
        far = (int)(~(unsigned int)k2);
    }
    __syncthreads();
    if (tid < NUM_G) cidx[b * NUM_G + tid] = clds[tid];
}

// ---------------- Phase B: KNN — one wave per group, XCD-swizzled (unchanged) ----------------
__device__ __forceinline__ void merge2(unsigned long long& a1, unsigned long long& a2,
                                       unsigned long long o1, unsigned long long o2) {
    unsigned long long hi = a1 > o1 ? a1 : o1;
    a1 = a1 < o1 ? a1 : o1;
    unsigned long long lo2 = a2 < o2 ? a2 : o2;
    a2 = hi < lo2 ? hi : lo2;
}
__device__ __forceinline__ void top2upd(unsigned long long& b1, unsigned long long& b2,
                                        unsigned long long v) {
    unsigned long long hi = b1 > v ? b1 : v;
    b1 = b1 < v ? b1 : v;
    b2 = b2 < hi ? b2 : hi;
}

__global__ __launch_bounds__(64)
__attribute__((amdgpu_waves_per_eu(4, 4)))
void knn_kernel(const float* __restrict__ pcd,
                const int* __restrict__ cidx,
                float* __restrict__ xout) {
    const int b = blockIdx.x & 31;
    const int g = blockIdx.x >> 5;
    const int bg_out = b * NUM_G + g;
    const int lane = threadIdx.x;
    const float* xb = pcd + (size_t)b * 6 * N_PTS;

    const int ci = cidx[bg_out];
    const float cx = xb[ci], cy = xb[N_PTS + ci], cz = xb[2 * N_PTS + ci];

    const float4* X4 = (const float4*)xb;
    const float4* Y4 = (const float4*)(xb + N_PTS);
    const float4* Z4 = (const float4*)(xb + 2 * N_PTS);

    unsigned long long b1 = ~0ull, b2 = ~0ull;
#pragma unroll 8
    for (int j = 0; j < 64; ++j) {
        float4 xv = X4[j * 64 + lane];
        float4 yv = Y4[j * 64 + lane];
        float4 zv = Z4[j * 64 + lane];
        float xs4[4] = {xv.x, xv.y, xv.z, xv.w};
        float ys4[4] = {yv.x, yv.y, yv.z, yv.w};
        float zs4[4] = {zv.x, zv.y, zv.z, zv.w};
        unsigned int p = (unsigned int)(j * 256 + lane * 4);
#pragma unroll
        for (int u = 0; u < 4; ++u) {
            float dx = __fsub_rn(cx, xs4[u]);
            float dy = __fsub_rn(cy, ys4[u]);
            float dz = __fsub_rn(cz, zs4[u]);
            float d = __fadd_rn(__fadd_rn(__fmul_rn(dx, dx), __fmul_rn(dy, dy)),
                                __fmul_rn(dz, dz));
            top2upd(b1, b2, ((unsigned long long)__float_as_uint(d) << 32) | (p + u));
        }
    }

    unsigned long long rm0 = 0, rm1 = 0, rm2 = 0, rm3 = 0;
    __shared__ int knn_sh[GRP_K];

    for (int r = 0; r < 16; ++r) {
        unsigned long long r1 = b1, r2 = b2;
#pragma unroll
        for (int m = 1; m < 64; m <<= 1) {
            unsigned long long o1 = __shfl_xor(r1, m, 64);
            unsigned long long o2 = __shfl_xor(r2, m, 64);
            merge2(r1, r2, o1, o2);
        }
        const int q1 = (int)(unsigned int)r1;
        const int q2 = (int)(unsigned int)r2;
        if (lane == 0) { knn_sh[2 * r] = q1; knn_sh[2 * r + 1] = q2; }

        const int wl1 = (q1 >> 2) & 63, s1 = ((q1 >> 8) << 2) | (q1 & 3);
        const int wl2 = (q2 >> 2) & 63, s2 = ((q2 >> 8) << 2) | (q2 & 3);
        {
            unsigned long long bit1 = 1ull << (s1 & 63);
            unsigned long long bit2 = 1ull << (s2 & 63);
            if (lane == wl1) {
                rm0 |= ((s1 >> 6) == 0) ? bit1 : 0ull;
                rm1 |= ((s1 >> 6) == 1) ? bit1 : 0ull;
                rm2 |= ((s1 >> 6) == 2) ? bit1 : 0ull;
                rm3 |= ((s1 >> 6) == 3) ? bit1 : 0ull;
            }
            if (lane == wl2) {
                rm0 |= ((s2 >> 6) == 0) ? bit2 : 0ull;
                rm1 |= ((s2 >> 6) == 1) ? bit2 : 0ull;
                rm2 |= ((s2 >> 6) == 2) ? bit2 : 0ull;
                rm3 |= ((s2 >> 6) == 3) ? bit2 : 0ull;
            }
        }

#pragma unroll 1
        for (int s = 0; s < 2; ++s) {
            if (s == 1 && wl2 == wl1) break;
            const int wl = s ? wl2 : wl1;
            unsigned long long m0 = __shfl(rm0, wl, 64);
            unsigned long long m1 = __shfl(rm1, wl, 64);
            unsigned long long m2 = __shfl(rm2, wl, 64);
            unsigned long long m3 = __shfl(rm3, wl, 64);
            const int wsel = lane >> 4;
            unsigned long long mw = wsel == 0 ? m0 : (wsel == 1 ? m1 : (wsel == 2 ? m2 : m3));
            float4 xv = X4[lane * 64 + wl];
            float4 yv = Y4[lane * 64 + wl];
            float4 zv = Z4[lane * 64 + wl];
            float xs4[4] = {xv.x, xv.y, xv.z, xv.w};
            float ys4[4] = {yv.x, yv.y, yv.z, yv.w};
            float zs4[4] = {zv.x, zv.y, zv.z, zv.w};
            unsigned int p = (unsigned int)(lane * 256 + wl * 4);
            unsigned long long s1v = ~0ull, s2v = ~0ull;
#pragma unroll
            for (int u = 0; u < 4; ++u) {
                float dx = __fsub_rn(cx, xs4[u]);
                float dy = __fsub_rn(cy, ys4[u]);
                float dz = __fsub_rn(cz, zs4[u]);
                float d = __fadd_rn(__fadd_rn(__fmul_rn(dx, dx), __fmul_rn(dy, dy)),
                                    __fmul_rn(dz, dz));
                unsigned long long v =
                    ((unsigned long long)__float_as_uint(d) << 32) | (p + u);
                if ((mw >> (((lane & 15) << 2) | u)) & 1ull) v = ~0ull;
                top2upd(s1v, s2v, v);
            }
#pragma unroll
            for (int m = 1; m < 64; m <<= 1) {
                unsigned long long o1 = __shfl_xor(s1v, m, 64);
                unsigned long long o2 = __shfl_xor(s2v, m, 64);
                merge2(s1v, s2v, o1, o2);
            }
            if (lane == wl) { b1 = s1v; b2 = s2v; }
        }
    }
    __syncthreads();

#pragma unroll
    for (int t = 0; t < 3; ++t) {
        int i = lane + 64 * t;
        int k = i / 6, c = i % 6;
        int p = knn_sh[k];
        float val = xb[c * N_PTS + p];
        if (c == 0) val = __fsub_rn(val, cx);
        else if (c == 1) val = __fsub_rn(val, cy);
        else if (c == 2) val = __fsub_rn(val, cz);
        xout[(size_t)bg_out * 192 + i] = val;
    }
}

// ---------------- Prep: LDS-tiled transpose fp32[K][N] -> bf16[N][K] (unchanged) ----------------
__global__ __launch_bounds__(256) void prep_kernel(const float* __restrict__ w2,
                                                   const float* __restrict__ w3,
                                                   const float* __restrict__ w4,
                                                   unsigned short* __restrict__ w2t,
                                                   unsigned short* __restrict__ w3t,
                                                   unsigned short* __restrict__ w4t) {
    const int tile = blockIdx.x;
    const float* src;
    unsigned short* dst;
    int K, N, kt, nt;
    if (tile < 8) {
        src = w2; dst = w2t; K = 128; N = 256;
        kt = tile >> 2; nt = tile & 3;
    } else if (tile < 72) {
        int t2 = tile - 8;
        src = w3; dst = w3t; K = 512; N = 512;
        kt = t2 >> 3; nt = t2 & 7;
    } else {
        int t2 = tile - 72;
        src = w4; dst = w4t; K = 512; N = 384;
        kt = t2 / 6; nt = t2 % 6;
    }
    const int k0 = kt * 64, n0 = nt * 64;

    __shared__ unsigned short tl[64][72];

    const int c = threadIdx.x & 63, r0 = threadIdx.x >> 6;
#pragma unroll
    for (int i = 0; i < 16; ++i) {
        int r = 4 * i + r0;
        tl[r][c] = f2bf(src[(size_t)(k0 + r) * N + n0 + c]);
    }
    __syncthreads();

    const int n = threadIdx.x >> 2;
    const int kc = (threadIdx.x & 3) * 16;
    u16x8 v0, v1;
#pragma unroll
    for (int j = 0; j < 8; ++j) {
        v0[j] = tl[kc + j][n];
        v1[j] = tl[kc + 8 + j][n];
    }
    *(u16x8*)(dst + (size_t)(n0 + n) * K + k0 + kc) = v0;
    *(u16x8*)(dst + (size_t)(n0 + n) * K + k0 + kc + 8) = v1;
}

// ---------------- Phase C v3: M=128 mega-block, 1024 thr / 16 waves ----------------
// Wave = (wc = w&7: col-slice, mh2 = w>>3: row-half of 64). Same MFMA count and
// per-output accumulation order as v2 (bit-exact); 4 waves/SIMD (vs 2) to hide
// the L2 weight-stream latency that held v2 at ~6% of MFMA peak.
__global__ __launch_bounds__(1024, 4) void mlp_mfma_kernel(
    const float* __restrict__ xin,
    const float* __restrict__ w1, const float* __restrict__ b1,
    const float* __restrict__ g1, const float* __restrict__ be1,
    const float* __restrict__ m1, const float* __restrict__ v1,
    const unsigned short* __restrict__ w2t, const float* __restrict__ b2,
    const unsigned short* __restrict__ w3t, const float* __restrict__ b3,
    const float* __restrict__ g2, const float* __restrict__ be2,
    const float* __restrict__ m2, const float* __restrict__ v2,
    const unsigned short* __restrict__ w4t, const float* __restrict__ b4,
    float* __restrict__ out) {
    const int g0 = blockIdx.x * 4;
    const int t = threadIdx.x;
    const int w16 = t >> 6;          // 0..15
    const int wc = w16 & 7;          // col-slice owner
    const int mh2 = w16 >> 3;        // row half (0: rows 0-63, 1: rows 64-127)
    const int lane = t & 63;
    const int lr = lane & 15;
    const int lq = lane >> 4;

    __shared__ __align__(16) unsigned short f2s[128 * 264];
    __shared__ __align__(16) unsigned short ubuf[128 * 136];
    __shared__ __align__(16) unsigned short fgs[4 * 256];
    __shared__ float xs[4 * 192];

    unsigned short* f1s = ubuf;
    unsigned short* f3c = ubuf;

    if (t < 768) xs[t] = xin[(size_t)g0 * 192 + t];
    __syncthreads();

    // ---- L1 + L2 in two row-halves of 64 ----
    {
        const int d = t & 127, rq = t >> 7;  // rq 0..7
        float wv[6];
#pragma unroll
        for (int c = 0; c < 6; ++c) wv[c] = w1[c * 128 + d];
        const float sc = g1[d] * rsqrtf(v1[d] + EPSF);
        const float sh = be1[d] - m1[d] * sc;
        const float bias = b1[d];

        for (int s = 0; s < 2; ++s) {
#pragma unroll
            for (int j = 0; j < 8; ++j) {
                const int rl = rq * 8 + j;
                const int gr = s * 64 + rl;
                const int g = gr >> 5, k = gr & 31;
                float acc = bias;
#pragma unroll
                for (int c = 0; c < 6; ++c) acc += xs[g * 192 + k * 6 + c] * wv[c];
                f1s[rl * 136 + d] = f2bf(fmaxf(acc * sc + sh, 0.0f));
            }
            __syncthreads();
            // L2: wave w16 owns cols [16*w16, 16*w16+16) over this half's 64 rows
            f32x4 acc[4];
            {
                f32x4 bq = *(const f32x4*)(b2 + w16 * 16 + lq * 4);
#pragma unroll
                for (int mtl = 0; mtl < 4; ++mtl) acc[mtl] = bq;
            }
#pragma unroll
            for (int ks = 0; ks < 4; ++ks) {
                bf16x8 xf[4];
#pragma unroll
                for (int mtl = 0; mtl < 4; ++mtl)
                    xf[mtl] = *(const bf16x8*)(f1s + (mtl * 16 + lr) * 136 + ks * 32 + lq * 8);
                bf16x8 wf = *(const bf16x8*)(w2t + (w16 * 16 + lr) * 128 + ks * 32 + lq * 8);
#pragma unroll
                for (int mtl = 0; mtl < 4; ++mtl)
                    acc[mtl] = __builtin_amdgcn_mfma_f32_16x16x32_bf16(wf, xf[mtl], acc[mtl], 0, 0, 0);
            }
#pragma unroll
            for (int mtl = 0; mtl < 4; ++mtl) {
                bf16x4 p;
#pragma unroll
                for (int r = 0; r < 4; ++r) p[r] = (short)f2bf(acc[mtl][r]);
                *(bf16x4*)(f2s + (size_t)(s * 64 + mtl * 16 + lr) * 264 + w16 * 16 + lq * 4) = p;
            }
            __syncthreads();
        }
    }

    // ---- fg = column max per group (1024 threads = 1024 cells) ----
    {
        int g = t >> 8, n = t & 255;
        float m = -3.9e38f;
#pragma unroll
        for (int k = 0; k < 32; ++k) m = fmaxf(m, bf2f(f2s[(size_t)(g * 32 + k) * 264 + n]));
        fgs[g * 256 + n] = f2bf(m);
    }
    __syncthreads();

    auto ldw3 = [&](int cb_, int ks_) -> bf16x8 {
        return *(const bf16x8*)(w3t + (size_t)(cb_ * 128 + wc * 16 + lr) * 512 + ks_ * 32 + lq * 8);
    };
    auto ldw4 = [&](int cb_, int kl_, int nti_) -> bf16x8 {
        return *(const bf16x8*)(w4t + (size_t)(wc * 48 + nti_ * 16 + lr) * 512 + cb_ * 128 + kl_ * 32 + lq * 8);
    };

    f32x4 acc4[3][4];
#pragma unroll
    for (int nti = 0; nti < 3; ++nti) {
        f32x4 bq = *(const f32x4*)(b4 + wc * 48 + nti * 16 + lq * 4);
#pragma unroll
        for (int mt = 0; mt < 4; ++mt) acc4[nti][mt] = bq;
    }

    for (int cb = 0; cb < 4; ++cb) {
        bf16x8 wp[4];
#pragma unroll
        for (int kp = 0; kp < 4; ++kp) wp[kp] = ldw3(cb, kp);

        // H phase (both row-half waves compute the same h — cheap redundancy)
        f32x4 accH = *(const f32x4*)(b3 + cb * 128 + wc * 16 + lq * 4);
#pragma unroll
        for (int ks = 0; ks < 8; ++ks) {
            bf16x8 wf = wp[ks & 3];
            wp[ks & 3] = ldw3(cb, ks + 4);
            bf16x8 xfh = *(const bf16x8*)(fgs + (lr & 3) * 256 + ks * 32 + lq * 8);
            accH = __builtin_amdgcn_mfma_f32_16x16x32_bf16(wf, xfh, accH, 0, 0, 0);
        }
        f32x4 acc3[4];
#pragma unroll
        for (int mt = 0; mt < 4; ++mt) {
            const int gg = mh2 * 2 + (mt >> 1);
#pragma unroll
            for (int r = 0; r < 4; ++r)
                acc3[mt][r] = __shfl(accH[r], (lane & 48) | gg, 64);
        }
        // main phase: ks 8..16, this half's f2 rows
#pragma unroll
        for (int ks = 8; ks < 16; ++ks) {
            bf16x8 wf = wp[ks & 3];
            if (ks + 4 < 16) wp[ks & 3] = ldw3(cb, ks + 4);
#pragma unroll
            for (int mt = 0; mt < 4; ++mt) {
                bf16x8 xf = *(const bf16x8*)(f2s + (size_t)(mh2 * 64 + mt * 16 + lr) * 264 + (ks - 8) * 32 + lq * 8);
                acc3[mt] = __builtin_amdgcn_mfma_f32_16x16x32_bf16(wf, xf, acc3[mt], 0, 0, 0);
            }
        }
        // bn2 + relu -> f3c
        {
            const int nq = cb * 128 + wc * 16 + lq * 4;
            f32x4 g2q = *(const f32x4*)(g2 + nq);
            f32x4 v2q = *(const f32x4*)(v2 + nq);
            f32x4 m2q = *(const f32x4*)(m2 + nq);
            f32x4 beq = *(const f32x4*)(be2 + nq);
            f32x4 sc, sh;
#pragma unroll
            for (int r = 0; r < 4; ++r) {
                sc[r] = g2q[r] * rsqrtf(v2q[r] + EPSF);
                sh[r] = beq[r] - m2q[r] * sc[r];
            }
#pragma unroll
            for (int mt = 0; mt < 4; ++mt) {
                bf16x4 p;
#pragma unroll
                for (int r = 0; r < 4; ++r)
                    p[r] = (short)f2bf(fmaxf(acc3[mt][r] * sc[r] + sh[r], 0.0f));
                *(bf16x4*)(f3c + (size_t)(mh2 * 64 + mt * 16 + lr) * 136 + wc * 16 + lq * 4) = p;
            }
        }
        __syncthreads();
        // L4 partial over this chunk's 128 k (JIT loads; 4-wave TLP hides latency)
        for (int kl = 0; kl < 4; ++kl) {
            bf16x8 w4f[3];
#pragma unroll
            for (int nti = 0; nti < 3; ++nti) w4f[nti] = ldw4(cb, kl, nti);
            bf16x8 xf4[4];
#pragma unroll
            for (int mt = 0; mt < 4; ++mt)
                xf4[mt] = *(const bf16x8*)(f3c + (size_t)(mh2 * 64 + mt * 16 + lr) * 136 + kl * 32 + lq * 8);
#pragma unroll
            for (int nti = 0; nti < 3; ++nti)
#pragma unroll
                for (int mt = 0; mt < 4; ++mt)
                    acc4[nti][mt] = __builtin_amdgcn_mfma_f32_16x16x32_bf16(w4f[nti], xf4[mt], acc4[nti][mt], 0, 0, 0);
        }
        __syncthreads();
    }

    // ---- max over 32 points per group, write out (each wave: its 2 groups) ----
#pragma unroll
    for (int nti = 0; nti < 3; ++nti) {
#pragma unroll
        for (int gl = 0; gl < 2; ++gl) {
            const int gg = mh2 * 2 + gl;
            f32x4 vv;
#pragma unroll
            for (int r = 0; r < 4; ++r)
                vv[r] = fmaxf(acc4[nti][2 * gl][r], acc4[nti][2 * gl + 1][r]);
#pragma unroll
            for (int mask = 1; mask <= 8; mask <<= 1) {
#pragma unroll
                for (int r = 0; r < 4; ++r)
                    vv[r] = fmaxf(vv[r], __shfl_xor(vv[r], mask, 64));
            }
            if (lr == 0)
                *(f32x4*)(out + (size_t)(g0 + gg) * 384 + wc * 48 + nti * 16 + lq * 4) = vv;
        }
    }
}

extern "C" void kernel_launch(void* const* d_in, const int* in_sizes, int n_in,
                              void* d_out, int out_size, void* d_ws, size_t ws_size,
                              hipStream_t stream) {
    const float* pcd = (const float*)d_in[0];
    const float* w1 = (const float*)d_in[2];
    const float* b1 = (const float*)d_in[3];
    const float* g1 = (const float*)d_in[4];
    const float* be1 = (const float*)d_in[5];
    const float* m1 = (const float*)d_in[6];
    const float* v1 = (const float*)d_in[7];
    const float* w2 = (const float*)d_in[8];
    const float* b2 = (const float*)d_in[9];
    const float* w3 = (const float*)d_in[10];
    const float* b3 = (const float*)d_in[11];
    const float* g2 = (const float*)d_in[12];
    const float* be2 = (const float*)d_in[13];
    const float* m2 = (const float*)d_in[14];
    const float* v2 = (const float*)d_in[15];
    const float* w4 = (const float*)d_in[16];
    const float* b4 = (const float*)d_in[17];
    float* out = (float*)d_out;

    char* ws = (char*)d_ws;
    int* cidx = (int*)ws;                                   // 8192 B
    float* xg = (float*)(ws + 8192);                        // 1,572,864 B
    unsigned short* w2t = (unsigned short*)(ws + 1581056);  // 65,536 B
    unsigned short* w3t = (unsigned short*)(ws + 1646592);  // 524,288 B
    unsigned short* w4t = (unsigned short*)(ws + 2170880);  // 393,216 B

    prep_kernel<<<120, 256, 0, stream>>>(w2, w3, w4, w2t, w3t, w4t);
    fps_kernel<<<32, 1024, 0, stream>>>(pcd, cidx);
    knn_kernel<<<2048, 64, 0, stream>>>(pcd, cidx, xg);
    mlp_mfma_kernel<<<512, 1024, 0, stream>>>(xg, w1, b1, g1, be1, m1, v1,
                                              w2t, b2, w3t, b3, g2, be2, m2, v2,
                                              w4t, b4, out);
}

// Round 13
// 395.932 us; speedup vs baseline: 1.1218x; 1.1218x over previous
//
#include <hip/hip_runtime.h>
#include <hip/hip_bf16.h>
#include <math.h>

#define N_PTS 16384
#define NUM_G 64
#define GRP_K 32
#define EPSF 1e-5f

typedef short bf16x8 __attribute__((ext_vector_type(8)));
typedef short bf16x4 __attribute__((ext_vector_type(4)));
typedef float f32x4 __attribute__((ext_vector_type(4)));
typedef unsigned short u16x8 __attribute__((ext_vector_type(8)));

__device__ __forceinline__ unsigned short f2bf(float x) {
    unsigned int u = __builtin_bit_cast(unsigned int, x);
    u = (u + 0x7FFFu + ((u >> 16) & 1u)) >> 16;
    return (unsigned short)u;
}
__device__ __forceinline__ float bf2f(unsigned short h) {
    unsigned int u = ((unsigned int)h) << 16;
    return __builtin_bit_cast(float, u);
}

// ---------------- Fused Phase A: FPS (blocks 0-31) + weight prep (blocks 32-151) ----------------
// fps occupies only 32 CUs; prep's 120 independent tile-blocks ride along on idle
// CUs in the same launch (saves a dispatch + ~10us). LDS: lxy 131KB + tl 9KB = 140KB.
__global__ __launch_bounds__(1024)
__attribute__((amdgpu_waves_per_eu(4, 4)))
void fps_prep_kernel(const float* __restrict__ pcd, int* __restrict__ cidx,
                     const float* __restrict__ w2, const float* __restrict__ w3,
                     const float* __restrict__ w4,
                     unsigned short* __restrict__ w2t,
                     unsigned short* __restrict__ w3t,
                     unsigned short* __restrict__ w4t) {
    __shared__ float2 lxy[N_PTS];               // 131,072 B (fps role)
    __shared__ unsigned long long wk[2][16];
    __shared__ int clds[NUM_G];
    __shared__ unsigned short tl[64][72];       // 9,216 B (prep role)

    const int tid = threadIdx.x;

    if (blockIdx.x >= 32) {
        // ---------- prep role: transpose fp32[K][N] -> bf16[N][K], 64x64 tile ----------
        if (tid < 256) {
            const int tile = blockIdx.x - 32;
            const float* src;
            unsigned short* dst;
            int K, N, kt, nt;
            if (tile < 8) {
                src = w2; dst = w2t; K = 128; N = 256;
                kt = tile >> 2; nt = tile & 3;
            } else if (tile < 72) {
                int t2 = tile - 8;
                src = w3; dst = w3t; K = 512; N = 512;
                kt = t2 >> 3; nt = t2 & 7;
            } else {
                int t2 = tile - 72;
                src = w4; dst = w4t; K = 512; N = 384;
                kt = t2 / 6; nt = t2 % 6;
            }
            const int k0 = kt * 64, n0 = nt * 64;
            const int c = tid & 63, r0 = tid >> 6;  // r0 0..3
#pragma unroll
            for (int i = 0; i < 16; ++i) {
                int r = 4 * i + r0;
                tl[r][c] = f2bf(src[(size_t)(k0 + r) * N + n0 + c]);
            }
            __syncthreads();
            const int n = tid >> 2;
            const int kc = (tid & 3) * 16;
            u16x8 v0, v1;
#pragma unroll
            for (int j = 0; j < 8; ++j) {
                v0[j] = tl[kc + j][n];
                v1[j] = tl[kc + 8 + j][n];
            }
            *(u16x8*)(dst + (size_t)(n0 + n) * K + k0 + kc) = v0;
            *(u16x8*)(dst + (size_t)(n0 + n) * K + k0 + kc + 8) = v1;
        } else {
            __syncthreads();  // match the prep role's single barrier
        }
        return;
    }

    // ---------- fps role (float2-LDS version, bit-exact numpy semantics) ----------
    const int b = blockIdx.x;
    const int lane = tid & 63, w = tid >> 6;
    const float* xb = pcd + (size_t)b * 6 * N_PTS;

    float dist[16], pzr[16];
#pragma unroll
    for (int j = 0; j < 16; ++j) {
        int p = tid + 1024 * j;
        float xv = xb[p];
        float yv = xb[N_PTS + p];
        lxy[p] = make_float2(xv, yv);
        pzr[j] = xb[2 * N_PTS + p];
        dist[j] = 1e10f;
    }
    __syncthreads();

    int far = 0;
    for (int it = 0; it < NUM_G; ++it) {
        int fu = __builtin_amdgcn_readfirstlane(far);
        float2 cxy = lxy[fu];
        float cz = xb[2 * N_PTS + fu];
        if (tid == 0) clds[it] = fu;

        float bv = -1.0f;
        int bj = 0;
#pragma unroll
        for (int j = 0; j < 16; ++j) {
            float2 q = lxy[tid + 1024 * j];
            float dx = __fsub_rn(q.x, cxy.x);
            float dy = __fsub_rn(q.y, cxy.y);
            float dz = __fsub_rn(pzr[j], cz);
            float d = __fadd_rn(__fadd_rn(__fmul_rn(dx, dx), __fmul_rn(dy, dy)),
                                __fmul_rn(dz, dz));
            dist[j] = fminf(dist[j], d);
            if (dist[j] > bv) { bv = dist[j]; bj = j; }  // j asc => lowest idx on tie
        }
        unsigned long long kmax =
            ((unsigned long long)__float_as_uint(bv) << 32) |
            (unsigned int)~(tid + 1024 * bj);
#pragma unroll
        for (int m = 1; m < 64; m <<= 1) {
            unsigned long long o = __shfl_xor(kmax, m, 64);
            kmax = o > kmax ? o : kmax;
        }
        if (lane == 0) wk[it & 1][w] = kmax;
        __syncthreads();
        unsigned long long k2 = (lane < 16) ? wk[it & 1][lane] : 0ull;
#pragma unroll
        for (int m = 1; m < 16; m <<= 1) {
            unsigned long long o = __shfl_xor(k2, m, 64);
            k2 = o > k2 ? o : k2;
        }
        k2 = __shfl(k2, 0, 64);
        far = (int)(~(unsigned int)k2);
    }
    __syncthreads();
    if (tid < NUM_G) cidx[b * NUM_G + tid] = clds[tid];
}

// ---------------- Phase B: KNN — one wave per group, XCD-swizzled (unchanged) ----------------
__device__ __forceinline__ void merge2(unsigned long long& a1, unsigned long long& a2,
                                       unsigned long long o1, unsigned long long o2) {
    unsigned long long hi = a1 > o1 ? a1 : o1;
    a1 = a1 < o1 ? a1 : o1;
    unsigned long long lo2 = a2 < o2 ? a2 : o2;
    a2 = hi < lo2 ? hi : lo2;
}
__device__ __forceinline__ void top2upd(unsigned long long& b1, unsigned long long& b2,
                                        unsigned long long v) {
    unsigned long long hi = b1 > v ? b1 : v;
    b1 = b1 < v ? b1 : v;
    b2 = b2 < hi ? b2 : hi;
}

__global__ __launch_bounds__(64)
__attribute__((amdgpu_waves_per_eu(4, 4)))
void knn_kernel(const float* __restrict__ pcd,
                const int* __restrict__ cidx,
                float* __restrict__ xout) {
    const int b = blockIdx.x & 31;
    const int g = blockIdx.x >> 5;
    const int bg_out = b * NUM_G + g;
    const int lane = threadIdx.x;
    const float* xb = pcd + (size_t)b * 6 * N_PTS;

    const int ci = cidx[bg_out];
    const float cx = xb[ci], cy = xb[N_PTS + ci], cz = xb[2 * N_PTS + ci];

    const float4* X4 = (const float4*)xb;
    const float4* Y4 = (const float4*)(xb + N_PTS);
    const float4* Z4 = (const float4*)(xb + 2 * N_PTS);

    unsigned long long b1 = ~0ull, b2 = ~0ull;
#pragma unroll 8
    for (int j = 0; j < 64; ++j) {
        float4 xv = X4[j * 64 + lane];
        float4 yv = Y4[j * 64 + lane];
        float4 zv = Z4[j * 64 + lane];
        float xs4[4] = {xv.x, xv.y, xv.z, xv.w};
        float ys4[4] = {yv.x, yv.y, yv.z, yv.w};
        float zs4[4] = {zv.x, zv.y, zv.z, zv.w};
        unsigned int p = (unsigned int)(j * 256 + lane * 4);
#pragma unroll
        for (int u = 0; u < 4; ++u) {
            float dx = __fsub_rn(cx, xs4[u]);
            float dy = __fsub_rn(cy, ys4[u]);
            float dz = __fsub_rn(cz, zs4[u]);
            float d = __fadd_rn(__fadd_rn(__fmul_rn(dx, dx), __fmul_rn(dy, dy)),
                                __fmul_rn(dz, dz));
            top2upd(b1, b2, ((unsigned long long)__float_as_uint(d) << 32) | (p + u));
        }
    }

    unsigned long long rm0 = 0, rm1 = 0, rm2 = 0, rm3 = 0;
    __shared__ int knn_sh[GRP_K];

    for (int r = 0; r < 16; ++r) {
        unsigned long long r1 = b1, r2 = b2;
#pragma unroll
        for (int m = 1; m < 64; m <<= 1) {
            unsigned long long o1 = __shfl_xor(r1, m, 64);
            unsigned long long o2 = __shfl_xor(r2, m, 64);
            merge2(r1, r2, o1, o2);
        }
        const int q1 = (int)(unsigned int)r1;
        const int q2 = (int)(unsigned int)r2;
        if (lane == 0) { knn_sh[2 * r] = q1; knn_sh[2 * r + 1] = q2; }

        const int wl1 = (q1 >> 2) & 63, s1 = ((q1 >> 8) << 2) | (q1 & 3);
        const int wl2 = (q2 >> 2) & 63, s2 = ((q2 >> 8) << 2) | (q2 & 3);
        {
            unsigned long long bit1 = 1ull << (s1 & 63);
            unsigned long long bit2 = 1ull << (s2 & 63);
            if (lane == wl1) {
                rm0 |= ((s1 >> 6) == 0) ? bit1 : 0ull;
                rm1 |= ((s1 >> 6) == 1) ? bit1 : 0ull;
                rm2 |= ((s1 >> 6) == 2) ? bit1 : 0ull;
                rm3 |= ((s1 >> 6) == 3) ? bit1 : 0ull;
            }
            if (lane == wl2) {
                rm0 |= ((s2 >> 6) == 0) ? bit2 : 0ull;
                rm1 |= ((s2 >> 6) == 1) ? bit2 : 0ull;
                rm2 |= ((s2 >> 6) == 2) ? bit2 : 0ull;
                rm3 |= ((s2 >> 6) == 3) ? bit2 : 0ull;
            }
        }

#pragma unroll 1
        for (int s = 0; s < 2; ++s) {
            if (s == 1 && wl2 == wl1) break;
            const int wl = s ? wl2 : wl1;
            unsigned long long m0 = __shfl(rm0, wl, 64);
            unsigned long long m1 = __shfl(rm1, wl, 64);
            unsigned long long m2 = __shfl(rm2, wl, 64);
            unsigned long long m3 = __shfl(rm3, wl, 64);
            const int wsel = lane >> 4;
            unsigned long long mw = wsel == 0 ? m0 : (wsel == 1 ? m1 : (wsel == 2 ? m2 : m3));
            float4 xv = X4[lane * 64 + wl];
            float4 yv = Y4[lane * 64 + wl];
            float4 zv = Z4[lane * 64 + wl];
            float xs4[4] = {xv.x, xv.y, xv.z, xv.w};
            float ys4[4] = {yv.x, yv.y, yv.z, yv.w};
            float zs4[4] = {zv.x, zv.y, zv.z, zv.w};
            unsigned int p = (unsigned int)(lane * 256 + wl * 4);
            unsigned long long s1v = ~0ull, s2v = ~0ull;
#pragma unroll
            for (int u = 0; u < 4; ++u) {
                float dx = __fsub_rn(cx, xs4[u]);
                float dy = __fsub_rn(cy, ys4[u]);
                float dz = __fsub_rn(cz, zs4[u]);
                float d = __fadd_rn(__fadd_rn(__fmul_rn(dx, dx), __fmul_rn(dy, dy)),
                                    __fmul_rn(dz, dz));
                unsigned long long v =
                    ((unsigned long long)__float_as_uint(d) << 32) | (p + u);
                if ((mw >> (((lane & 15) << 2) | u)) & 1ull) v = ~0ull;
                top2upd(s1v, s2v, v);
            }
#pragma unroll
            for (int m = 1; m < 64; m <<= 1) {
                unsigned long long o1 = __shfl_xor(s1v, m, 64);
                unsigned long long o2 = __shfl_xor(s2v, m, 64);
                merge2(s1v, s2v, o1, o2);
            }
            if (lane == wl) { b1 = s1v; b2 = s2v; }
        }
    }
    __syncthreads();

#pragma unroll
    for (int t = 0; t < 3; ++t) {
        int i = lane + 64 * t;
        int k = i / 6, c = i % 6;
        int p = knn_sh[k];
        float val = xb[c * N_PTS + p];
        if (c == 0) val = __fsub_rn(val, cx);
        else if (c == 1) val = __fsub_rn(val, cy);
        else if (c == 2) val = __fsub_rn(val, cz);
        xout[(size_t)bg_out * 192 + i] = val;
    }
}

// ---------------- Phase C: M=128 mega-block MFMA MLP (v2, 512 thr — reverted from 1024) ----------------
// R12 post-mortem: 1024-thr variant regressed (LDS conflicts 4.2M->11.3M, doubled
// weight L2 reads, VGPR squeeze). v2 is the proven configuration.
__global__ __launch_bounds__(512, 2) void mlp_mfma_kernel(
    const float* __restrict__ xin,
    const float* __restrict__ w1, const float* __restrict__ b1,
    const float* __restrict__ g1, const float* __restrict__ be1,
    const float* __restrict__ m1, const float* __restrict__ v1,
    const unsigned short* __restrict__ w2t, const float* __restrict__ b2,
    const unsigned short* __restrict__ w3t, const float* __restrict__ b3,
    const float* __restrict__ g2, const float* __restrict__ be2,
    const float* __restrict__ m2, const float* __restrict__ v2,
    const unsigned short* __restrict__ w4t, const float* __restrict__ b4,
    float* __restrict__ out) {
    const int g0 = blockIdx.x * 4;
    const int t = threadIdx.x;
    const int w = t >> 6;
    const int lane = t & 63;
    const int lr = lane & 15;
    const int lq = lane >> 4;

    __shared__ __align__(16) unsigned short f2s[128 * 264];
    __shared__ __align__(16) unsigned short ubuf[128 * 136];
    __shared__ __align__(16) unsigned short fgs[4 * 256];
    __shared__ float xs[4 * 192];

    unsigned short* f1s = ubuf;
    unsigned short* f3c = ubuf;

    for (int i = t; i < 768; i += 512) xs[i] = xin[(size_t)g0 * 192 + i];
    __syncthreads();

    {
        const int d = t & 127, rq = t >> 7;
        float wv[6];
#pragma unroll
        for (int c = 0; c < 6; ++c) wv[c] = w1[c * 128 + d];
        const float sc = g1[d] * rsqrtf(v1[d] + EPSF);
        const float sh = be1[d] - m1[d] * sc;
        const float bias = b1[d];

        for (int s = 0; s < 2; ++s) {
#pragma unroll
            for (int j = 0; j < 16; ++j) {
                const int rl = rq * 16 + j;
                const int gr = s * 64 + rl;
                const int g = gr >> 5, k = gr & 31;
                float acc = bias;
#pragma unroll
                for (int c = 0; c < 6; ++c) acc += xs[g * 192 + k * 6 + c] * wv[c];
                f1s[rl * 136 + d] = f2bf(fmaxf(acc * sc + sh, 0.0f));
            }
            __syncthreads();
            f32x4 acc[4][2];
#pragma unroll
            for (int nti = 0; nti < 2; ++nti) {
                f32x4 bq = *(const f32x4*)(b2 + w * 32 + nti * 16 + lq * 4);
#pragma unroll
                for (int mtl = 0; mtl < 4; ++mtl) acc[mtl][nti] = bq;
            }
#pragma unroll
            for (int ks = 0; ks < 4; ++ks) {
                bf16x8 xf[4], wf[2];
#pragma unroll
                for (int mtl = 0; mtl < 4; ++mtl)
                    xf[mtl] = *(const bf16x8*)(f1s + (mtl * 16 + lr) * 136 + ks * 32 + lq * 8);
#pragma unroll
                for (int nti = 0; nti < 2; ++nti)
                    wf[nti] = *(const bf16x8*)(w2t + (w * 32 + nti * 16 + lr) * 128 + ks * 32 + lq * 8);
#pragma unroll
                for (int mtl = 0; mtl < 4; ++mtl)
#pragma unroll
                    for (int nti = 0; nti < 2; ++nti)
                        acc[mtl][nti] = __builtin_amdgcn_mfma_f32_16x16x32_bf16(wf[nti], xf[mtl], acc[mtl][nti], 0, 0, 0);
            }
#pragma unroll
            for (int mtl = 0; mtl < 4; ++mtl)
#pragma unroll
                for (int nti = 0; nti < 2; ++nti) {
                    bf16x4 p;
#pragma unroll
                    for (int r = 0; r < 4; ++r) p[r] = (short)f2bf(acc[mtl][nti][r]);
                    *(bf16x4*)(f2s + (size_t)(s * 64 + mtl * 16 + lr) * 264 + w * 32 + nti * 16 + lq * 4) = p;
                }
            __syncthreads();
        }
    }

    for (int idx = t; idx < 1024; idx += 512) {
        int g = idx >> 8, n = idx & 255;
        float m = -3.9e38f;
#pragma unroll
        for (int k = 0; k < 32; ++k) m = fmaxf(m, bf2f(f2s[(size_t)(g * 32 + k) * 264 + n]));
        fgs[g * 256 + n] = f2bf(m);
    }
    __syncthreads();

    auto ldw3 = [&](int cb_, int ks_) -> bf16x8 {
        return *(const bf16x8*)(w3t + (size_t)(cb_ * 128 + w * 16 + lr) * 512 + ks_ * 32 + lq * 8);
    };
    auto ldw4 = [&](int cb_, int kl_, int nti_) -> bf16x8 {
        return *(const bf16x8*)(w4t + (size_t)(w * 48 + nti_ * 16 + lr) * 512 + cb_ * 128 + kl_ * 32 + lq * 8);
    };

    f32x4 acc4[3][8];
#pragma unroll
    for (int nti = 0; nti < 3; ++nti) {
        f32x4 bq = *(const f32x4*)(b4 + w * 48 + nti * 16 + lq * 4);
#pragma unroll
        for (int mt = 0; mt < 8; ++mt) acc4[nti][mt] = bq;
    }

    for (int cb = 0; cb < 4; ++cb) {
        bf16x8 wp[4];
#pragma unroll
        for (int kp = 0; kp < 4; ++kp) wp[kp] = ldw3(cb, kp);

        f32x4 accH = *(const f32x4*)(b3 + cb * 128 + w * 16 + lq * 4);
#pragma unroll
        for (int ks = 0; ks < 8; ++ks) {
            bf16x8 wf = wp[ks & 3];
            wp[ks & 3] = ldw3(cb, ks + 4);
            bf16x8 xfh = *(const bf16x8*)(fgs + (lr & 3) * 256 + ks * 32 + lq * 8);
            accH = __builtin_amdgcn_mfma_f32_16x16x32_bf16(wf, xfh, accH, 0, 0, 0);
        }
        f32x4 acc3[8];
#pragma unroll
        for (int mt = 0; mt < 8; ++mt) {
            const int gg = mt >> 1;
#pragma unroll
            for (int r = 0; r < 4; ++r)
                acc3[mt][r] = __shfl(accH[r], (lane & 48) | gg, 64);
        }
#pragma unroll
        for (int ks = 8; ks < 16; ++ks) {
            bf16x8 wf = wp[ks & 3];
            if (ks + 4 < 16) wp[ks & 3] = ldw3(cb, ks + 4);
#pragma unroll
            for (int mt = 0; mt < 8; ++mt) {
                bf16x8 xf = *(const bf16x8*)(f2s + (size_t)(mt * 16 + lr) * 264 + (ks - 8) * 32 + lq * 8);
                acc3[mt] = __builtin_amdgcn_mfma_f32_16x16x32_bf16(wf, xf, acc3[mt], 0, 0, 0);
            }
        }
        {
            const int nq = cb * 128 + w * 16 + lq * 4;
            f32x4 g2q = *(const f32x4*)(g2 + nq);
            f32x4 v2q = *(const f32x4*)(v2 + nq);
            f32x4 m2q = *(const f32x4*)(m2 + nq);
            f32x4 beq = *(const f32x4*)(be2 + nq);
            f32x4 sc, sh;
#pragma unroll
            for (int r = 0; r < 4; ++r) {
                sc[r] = g2q[r] * rsqrtf(v2q[r] + EPSF);
                sh[r] = beq[r] - m2q[r] * sc[r];
            }
#pragma unroll
            for (int mt = 0; mt < 8; ++mt) {
                bf16x4 p;
#pragma unroll
                for (int r = 0; r < 4; ++r)
                    p[r] = (short)f2bf(fmaxf(acc3[mt][r] * sc[r] + sh[r], 0.0f));
                *(bf16x4*)(f3c + (size_t)(mt * 16 + lr) * 136 + w * 16 + lq * 4) = p;
            }
        }
        bf16x8 w4a[3];
#pragma unroll
        for (int nti = 0; nti < 3; ++nti) w4a[nti] = ldw4(cb, 0, nti);
        __syncthreads();
        for (int kl = 0; kl < 4; ++kl) {
            bf16x8 w4n[3];
            if (kl < 3) {
#pragma unroll
                for (int nti = 0; nti < 3; ++nti) w4n[nti] = ldw4(cb, kl + 1, nti);
            }
            bf16x8 xf8[8];
#pragma unroll
            for (int mt = 0; mt < 8; ++mt)
                xf8[mt] = *(const bf16x8*)(f3c + (size_t)(mt * 16 + lr) * 136 + kl * 32 + lq * 8);
#pragma unroll
            for (int nti = 0; nti < 3; ++nti)
#pragma unroll
                for (int mt = 0; mt < 8; ++mt)
                    acc4[nti][mt] = __builtin_amdgcn_mfma_f32_16x16x32_bf16(w4a[nti], xf8[mt], acc4[nti][mt], 0, 0, 0);
            if (kl < 3) {
#pragma unroll
                for (int nti = 0; nti < 3; ++nti) w4a[nti] = w4n[nti];
            }
        }
        __syncthreads();
    }

#pragma unroll
    for (int nti = 0; nti < 3; ++nti) {
#pragma unroll
        for (int gg = 0; gg < 4; ++gg) {
            f32x4 vv;
#pragma unroll
            for (int r = 0; r < 4; ++r)
                vv[r] = fmaxf(acc4[nti][2 * gg][r], acc4[nti][2 * gg + 1][r]);
#pragma unroll
            for (int mask = 1; mask <= 8; mask <<= 1) {
#pragma unroll
                for (int r = 0; r < 4; ++r)
                    vv[r] = fmaxf(vv[r], __shfl_xor(vv[r], mask, 64));
            }
            if (lr == 0)
                *(f32x4*)(out + (size_t)(g0 + gg) * 384 + w * 48 + nti * 16 + lq * 4) = vv;
        }
    }
}

extern "C" void kernel_launch(void* const* d_in, const int* in_sizes, int n_in,
                              void* d_out, int out_size, void* d_ws, size_t ws_size,
                              hipStream_t stream) {
    const float* pcd = (const float*)d_in[0];
    const float* w1 = (const float*)d_in[2];
    const float* b1 = (const float*)d_in[3];
    const float* g1 = (const float*)d_in[4];
    const float* be1 = (const float*)d_in[5];
    const float* m1 = (const float*)d_in[6];
    const float* v1 = (const float*)d_in[7];
    const float* w2 = (const float*)d_in[8];
    const float* b2 = (const float*)d_in[9];
    const float* w3 = (const float*)d_in[10];
    const float* b3 = (const float*)d_in[11];
    const float* g2 = (const float*)d_in[12];
    const float* be2 = (const float*)d_in[13];
    const float* m2 = (const float*)d_in[14];
    const float* v2 = (const float*)d_in[15];
    const float* w4 = (const float*)d_in[16];
    const float* b4 = (const float*)d_in[17];
    float* out = (float*)d_out;

    char* ws = (char*)d_ws;
    int* cidx = (int*)ws;                                   // 8192 B
    float* xg = (float*)(ws + 8192);                        // 1,572,864 B
    unsigned short* w2t = (unsigned short*)(ws + 1581056);  // 65,536 B
    unsigned short* w3t = (unsigned short*)(ws + 1646592);  // 524,288 B
    unsigned short* w4t = (unsigned short*)(ws + 2170880);  // 393,216 B

    fps_prep_kernel<<<152, 1024, 0, stream>>>(pcd, cidx, w2, w3, w4, w2t, w3t, w4t);
    knn_kernel<<<2048, 64, 0, stream>>>(pcd, cidx, xg);
    mlp_mfma_kernel<<<512, 512, 0, stream>>>(xg, w1, b1, g1, be1, m1, v1,
                                             w2t, b2, w3t, b3, g2, be2, m2, v2,
                                             w4t, b4, out);
}

// Round 14
// 386.168 us; speedup vs baseline: 1.1502x; 1.0253x over previous
//
#include <hip/hip_runtime.h>
#include <hip/hip_bf16.h>
#include <math.h>

#define N_PTS 16384
#define NUM_G 64
#define GRP_K 32
#define EPSF 1e-5f

typedef short bf16x8 __attribute__((ext_vector_type(8)));
typedef short bf16x4 __attribute__((ext_vector_type(4)));
typedef float f32x4 __attribute__((ext_vector_type(4)));
typedef unsigned short u16x8 __attribute__((ext_vector_type(8)));

__device__ __forceinline__ unsigned short f2bf(float x) {
    unsigned int u = __builtin_bit_cast(unsigned int, x);
    u = (u + 0x7FFFu + ((u >> 16) & 1u)) >> 16;
    return (unsigned short)u;
}
__device__ __forceinline__ float bf2f(unsigned short h) {
    unsigned int u = ((unsigned int)h) << 16;
    return __builtin_bit_cast(float, u);
}

// ---------------- Fused Phase A: FPS v5 (blocks 0-31) + weight prep (blocks 32-151) ----------------
// R13 model: scan and shuffles shared the LDS pipe (~600 LDS-instr/CU/iter = the
// measured 5000 cyc/iter). v5: (1) chunked ownership p in [tid*16,tid*16+16) ->
// coords re-loaded EXPLICITLY each iter as 12 float4 VMEM (L2-resident, no LDS);
// (2) tid-order == idx-order => wave argmax = f32 butterfly (6 shfl) + ballot +
// ffsll + readlane — exact numpy tie-break, half the bpermutes. dist[16] in regs.
__global__ __launch_bounds__(1024)
__attribute__((amdgpu_waves_per_eu(4, 4)))
void fps_prep_kernel(const float* __restrict__ pcd, int* __restrict__ cidx,
                     const float* __restrict__ w2, const float* __restrict__ w3,
                     const float* __restrict__ w4,
                     unsigned short* __restrict__ w2t,
                     unsigned short* __restrict__ w3t,
                     unsigned short* __restrict__ w4t) {
    __shared__ unsigned long long wk[2][16];
    __shared__ int clds[NUM_G];
    __shared__ unsigned short tl[64][72];       // prep role

    const int tid = threadIdx.x;

    if (blockIdx.x >= 32) {
        // ---------- prep role: transpose fp32[K][N] -> bf16[N][K], 64x64 tile ----------
        if (tid < 256) {
            const int tile = blockIdx.x - 32;
            const float* src;
            unsigned short* dst;
            int K, N, kt, nt;
            if (tile < 8) {
                src = w2; dst = w2t; K = 128; N = 256;
                kt = tile >> 2; nt = tile & 3;
            } else if (tile < 72) {
                int t2 = tile - 8;
                src = w3; dst = w3t; K = 512; N = 512;
                kt = t2 >> 3; nt = t2 & 7;
            } else {
                int t2 = tile - 72;
                src = w4; dst = w4t; K = 512; N = 384;
                kt = t2 / 6; nt = t2 % 6;
            }
            const int k0 = kt * 64, n0 = nt * 64;
            const int c = tid & 63, r0 = tid >> 6;
#pragma unroll
            for (int i = 0; i < 16; ++i) {
                int r = 4 * i + r0;
                tl[r][c] = f2bf(src[(size_t)(k0 + r) * N + n0 + c]);
            }
            __syncthreads();
            const int n = tid >> 2;
            const int kc = (tid & 3) * 16;
            u16x8 v0, v1;
#pragma unroll
            for (int j = 0; j < 8; ++j) {
                v0[j] = tl[kc + j][n];
                v1[j] = tl[kc + 8 + j][n];
            }
            *(u16x8*)(dst + (size_t)(n0 + n) * K + k0 + kc) = v0;
            *(u16x8*)(dst + (size_t)(n0 + n) * K + k0 + kc + 8) = v1;
        } else {
            __syncthreads();
        }
        return;
    }

    // ---------- fps role ----------
    const int b = blockIdx.x;
    const int lane = tid & 63, w = tid >> 6;
    const float* xb = pcd + (size_t)b * 6 * N_PTS;
    const float4* Xc = (const float4*)xb;
    const float4* Yc = (const float4*)(xb + N_PTS);
    const float4* Zc = (const float4*)(xb + 2 * N_PTS);

    float dist[16];
#pragma unroll
    for (int j = 0; j < 16; ++j) dist[j] = 1e10f;

    int far = 0;
    for (int it = 0; it < NUM_G; ++it) {
        int fu = __builtin_amdgcn_readfirstlane(far);
        float cx = xb[fu], cy = xb[N_PTS + fu], cz = xb[2 * N_PTS + fu];
        if (tid == 0) clds[it] = fu;

        float bv = -1.0f;
        int bj = 0;
#pragma unroll
        for (int jp = 0; jp < 4; ++jp) {
            float4 xq = Xc[tid * 4 + jp];
            float4 yq = Yc[tid * 4 + jp];
            float4 zq = Zc[tid * 4 + jp];
            float xa[4] = {xq.x, xq.y, xq.z, xq.w};
            float ya[4] = {yq.x, yq.y, yq.z, yq.w};
            float za[4] = {zq.x, zq.y, zq.z, zq.w};
#pragma unroll
            for (int u = 0; u < 4; ++u) {
                const int j = jp * 4 + u;
                float dx = __fsub_rn(xa[u], cx);
                float dy = __fsub_rn(ya[u], cy);
                float dz = __fsub_rn(za[u], cz);
                float d = __fadd_rn(__fadd_rn(__fmul_rn(dx, dx), __fmul_rn(dy, dy)),
                                    __fmul_rn(dz, dz));
                dist[j] = fminf(dist[j], d);
                if (dist[j] > bv) { bv = dist[j]; bj = j; }  // j asc => lowest idx on tie
            }
        }
        // f32 max butterfly (6 shuffles; exact bit-copy propagation, all finite)
        float vmax = bv;
#pragma unroll
        for (int m = 1; m < 64; m <<= 1) {
            float o = __shfl_xor(vmax, m, 64);
            vmax = o > vmax ? o : vmax;
        }
        // lowest lane with bv==vmax has the lowest point index (tid-major chunks)
        unsigned long long mk = __ballot(bv == vmax);
        int fl = __ffsll((unsigned long long)mk) - 1;
        int bjw = __shfl(bj, fl, 64);
        int idx = (((w << 6) | fl) << 4) + bjw;
        unsigned long long key =
            ((unsigned long long)__float_as_uint(vmax) << 32) | (unsigned int)~idx;
        if (lane == 0) wk[it & 1][w] = key;
        __syncthreads();
        unsigned long long k2 = (lane < 16) ? wk[it & 1][lane] : 0ull;
#pragma unroll
        for (int m = 1; m < 16; m <<= 1) {
            unsigned long long o = __shfl_xor(k2, m, 64);
            k2 = o > k2 ? o : k2;
        }
        k2 = __shfl(k2, 0, 64);
        far = (int)(~(unsigned int)k2);
    }
    __syncthreads();
    if (tid < NUM_G) cidx[b * NUM_G + tid] = clds[tid];
}

// ---------------- Phase B: KNN — one wave per group, XCD-swizzled (unchanged) ----------------
__device__ __forceinline__ void merge2(unsigned long long& a1, unsigned long long& a2,
                                       unsigned long long o1, unsigned long long o2) {
    unsigned long long hi = a1 > o1 ? a1 : o1;
    a1 = a1 < o1 ? a1 : o1;
    unsigned long long lo2 = a2 < o2 ? a2 : o2;
    a2 = hi < lo2 ? hi : lo2;
}
__device__ __forceinline__ void top2upd(unsigned long long& b1, unsigned long long& b2,
                                        unsigned long long v) {
    unsigned long long hi = b1 > v ? b1 : v;
    b1 = b1 < v ? b1 : v;
    b2 = b2 < hi ? b2 : hi;
}

__global__ __launch_bounds__(64)
__attribute__((amdgpu_waves_per_eu(4, 4)))
void knn_kernel(const float* __restrict__ pcd,
                const int* __restrict__ cidx,
                float* __restrict__ xout) {
    const int b = blockIdx.x & 31;
    const int g = blockIdx.x >> 5;
    const int bg_out = b * NUM_G + g;
    const int lane = threadIdx.x;
    const float* xb = pcd + (size_t)b * 6 * N_PTS;

    const int ci = cidx[bg_out];
    const float cx = xb[ci], cy = xb[N_PTS + ci], cz = xb[2 * N_PTS + ci];

    const float4* X4 = (const float4*)xb;
    const float4* Y4 = (const float4*)(xb + N_PTS);
    const float4* Z4 = (const float4*)(xb + 2 * N_PTS);

    unsigned long long b1 = ~0ull, b2 = ~0ull;
#pragma unroll 8
    for (int j = 0; j < 64; ++j) {
        float4 xv = X4[j * 64 + lane];
        float4 yv = Y4[j * 64 + lane];
        float4 zv = Z4[j * 64 + lane];
        float xs4[4] = {xv.x, xv.y, xv.z, xv.w};
        float ys4[4] = {yv.x, yv.y, yv.z, yv.w};
        float zs4[4] = {zv.x, zv.y, zv.z, zv.w};
        unsigned int p = (unsigned int)(j * 256 + lane * 4);
#pragma unroll
        for (int u = 0; u < 4; ++u) {
            float dx = __fsub_rn(cx, xs4[u]);
            float dy = __fsub_rn(cy, ys4[u]);
            float dz = __fsub_rn(cz, zs4[u]);
            float d = __fadd_rn(__fadd_rn(__fmul_rn(dx, dx), __fmul_rn(dy, dy)),
                                __fmul_rn(dz, dz));
            top2upd(b1, b2, ((unsigned long long)__float_as_uint(d) << 32) | (p + u));
        }
    }

    unsigned long long rm0 = 0, rm1 = 0, rm2 = 0, rm3 = 0;
    __shared__ int knn_sh[GRP_K];

    for (int r = 0; r < 16; ++r) {
        unsigned long long r1 = b1, r2 = b2;
#pragma unroll
        for (int m = 1; m < 64; m <<= 1) {
            unsigned long long o1 = __shfl_xor(r1, m, 64);
            unsigned long long o2 = __shfl_xor(r2, m, 64);
            merge2(r1, r2, o1, o2);
        }
        const int q1 = (int)(unsigned int)r1;
        const int q2 = (int)(unsigned int)r2;
        if (lane == 0) { knn_sh[2 * r] = q1; knn_sh[2 * r + 1] = q2; }

        const int wl1 = (q1 >> 2) & 63, s1 = ((q1 >> 8) << 2) | (q1 & 3);
        const int wl2 = (q2 >> 2) & 63, s2 = ((q2 >> 8) << 2) | (q2 & 3);
        {
            unsigned long long bit1 = 1ull << (s1 & 63);
            unsigned long long bit2 = 1ull << (s2 & 63);
            if (lane == wl1) {
                rm0 |= ((s1 >> 6) == 0) ? bit1 : 0ull;
                rm1 |= ((s1 >> 6) == 1) ? bit1 : 0ull;
                rm2 |= ((s1 >> 6) == 2) ? bit1 : 0ull;
                rm3 |= ((s1 >> 6) == 3) ? bit1 : 0ull;
            }
            if (lane == wl2) {
                rm0 |= ((s2 >> 6) == 0) ? bit2 : 0ull;
                rm1 |= ((s2 >> 6) == 1) ? bit2 : 0ull;
                rm2 |= ((s2 >> 6) == 2) ? bit2 : 0ull;
                rm3 |= ((s2 >> 6) == 3) ? bit2 : 0ull;
            }
        }

#pragma unroll 1
        for (int s = 0; s < 2; ++s) {
            if (s == 1 && wl2 == wl1) break;
            const int wl = s ? wl2 : wl1;
            unsigned long long m0 = __shfl(rm0, wl, 64);
            unsigned long long m1 = __shfl(rm1, wl, 64);
            unsigned long long m2 = __shfl(rm2, wl, 64);
            unsigned long long m3 = __shfl(rm3, wl, 64);
            const int wsel = lane >> 4;
            unsigned long long mw = wsel == 0 ? m0 : (wsel == 1 ? m1 : (wsel == 2 ? m2 : m3));
            float4 xv = X4[lane * 64 + wl];
            float4 yv = Y4[lane * 64 + wl];
            float4 zv = Z4[lane * 64 + wl];
            float xs4[4] = {xv.x, xv.y, xv.z, xv.w};
            float ys4[4] = {yv.x, yv.y, yv.z, yv.w};
            float zs4[4] = {zv.x, zv.y, zv.z, zv.w};
            unsigned int p = (unsigned int)(lane * 256 + wl * 4);
            unsigned long long s1v = ~0ull, s2v = ~0ull;
#pragma unroll
            for (int u = 0; u < 4; ++u) {
                float dx = __fsub_rn(cx, xs4[u]);
                float dy = __fsub_rn(cy, ys4[u]);
                float dz = __fsub_rn(cz, zs4[u]);
                float d = __fadd_rn(__fadd_rn(__fmul_rn(dx, dx), __fmul_rn(dy, dy)),
                                    __fmul_rn(dz, dz));
                unsigned long long v =
                    ((unsigned long long)__float_as_uint(d) << 32) | (p + u);
                if ((mw >> (((lane & 15) << 2) | u)) & 1ull) v = ~0ull;
                top2upd(s1v, s2v, v);
            }
#pragma unroll
            for (int m = 1; m < 64; m <<= 1) {
                unsigned long long o1 = __shfl_xor(s1v, m, 64);
                unsigned long long o2 = __shfl_xor(s2v, m, 64);
                merge2(s1v, s2v, o1, o2);
            }
            if (lane == wl) { b1 = s1v; b2 = s2v; }
        }
    }
    __syncthreads();

#pragma unroll
    for (int t = 0; t < 3; ++t) {
        int i = lane + 64 * t;
        int k = i / 6, c = i % 6;
        int p = knn_sh[k];
        float val = xb[c * N_PTS + p];
        if (c == 0) val = __fsub_rn(val, cx);
        else if (c == 1) val = __fsub_rn(val, cy);
        else if (c == 2) val = __fsub_rn(val, cz);
        xout[(size_t)bg_out * 192 + i] = val;
    }
}

// ---------------- Phase C: M=128 mega-block MFMA MLP (v2, 512 thr — unchanged) ----------------
__global__ __launch_bounds__(512, 2) void mlp_mfma_kernel(
    const float* __restrict__ xin,
    const float* __restrict__ w1, const float* __restrict__ b1,
    const float* __restrict__ g1, const float* __restrict__ be1,
    const float* __restrict__ m1, const float* __restrict__ v1,
    const unsigned short* __restrict__ w2t, const float* __restrict__ b2,
    const unsigned short* __restrict__ w3t, const float* __restrict__ b3,
    const float* __restrict__ g2, const float* __restrict__ be2,
    const float* __restrict__ m2, const float* __restrict__ v2,
    const unsigned short* __restrict__ w4t, const float* __restrict__ b4,
    float* __restrict__ out) {
    const int g0 = blockIdx.x * 4;
    const int t = threadIdx.x;
    const int w = t >> 6;
    const int lane = t & 63;
    const int lr = lane & 15;
    const int lq = lane >> 4;

    __shared__ __align__(16) unsigned short f2s[128 * 264];
    __shared__ __align__(16) unsigned short ubuf[128 * 136];
    __shared__ __align__(16) unsigned short fgs[4 * 256];
    __shared__ float xs[4 * 192];

    unsigned short* f1s = ubuf;
    unsigned short* f3c = ubuf;

    for (int i = t; i < 768; i += 512) xs[i] = xin[(size_t)g0 * 192 + i];
    __syncthreads();

    {
        const int d = t & 127, rq = t >> 7;
        float wv[6];
#pragma unroll
        for (int c = 0; c < 6; ++c) wv[c] = w1[c * 128 + d];
        const float sc = g1[d] * rsqrtf(v1[d] + EPSF);
        const float sh = be1[d] - m1[d] * sc;
        const float bias = b1[d];

        for (int s = 0; s < 2; ++s) {
#pragma unroll
            for (int j = 0; j < 16; ++j) {
                const int rl = rq * 16 + j;
                const int gr = s * 64 + rl;
                const int g = gr >> 5, k = gr & 31;
                float acc = bias;
#pragma unroll
                for (int c = 0; c < 6; ++c) acc += xs[g * 192 + k * 6 + c] * wv[c];
                f1s[rl * 136 + d] = f2bf(fmaxf(acc * sc + sh, 0.0f));
            }
            __syncthreads();
            f32x4 acc[4][2];
#pragma unroll
            for (int nti = 0; nti < 2; ++nti) {
                f32x4 bq = *(const f32x4*)(b2 + w * 32 + nti * 16 + lq * 4);
#pragma unroll
                for (int mtl = 0; mtl < 4; ++mtl) acc[mtl][nti] = bq;
            }
#pragma unroll
            for (int ks = 0; ks < 4; ++ks) {
                bf16x8 xf[4], wf[2];
#pragma unroll
                for (int mtl = 0; mtl < 4; ++mtl)
                    xf[mtl] = *(const bf16x8*)(f1s + (mtl * 16 + lr) * 136 + ks * 32 + lq * 8);
#pragma unroll
                for (int nti = 0; nti < 2; ++nti)
                    wf[nti] = *(const bf16x8*)(w2t + (w * 32 + nti * 16 + lr) * 128 + ks * 32 + lq * 8);
#pragma unroll
                for (int mtl = 0; mtl < 4; ++mtl)
#pragma unroll
                    for (int nti = 0; nti < 2; ++nti)
                        acc[mtl][nti] = __builtin_amdgcn_mfma_f32_16x16x32_bf16(wf[nti], xf[mtl], acc[mtl][nti], 0, 0, 0);
            }
#pragma unroll
            for (int mtl = 0; mtl < 4; ++mtl)
#pragma unroll
                for (int nti = 0; nti < 2; ++nti) {
                    bf16x4 p;
#pragma unroll
                    for (int r = 0; r < 4; ++r) p[r] = (short)f2bf(acc[mtl][nti][r]);
                    *(bf16x4*)(f2s + (size_t)(s * 64 + mtl * 16 + lr) * 264 + w * 32 + nti * 16 + lq * 4) = p;
                }
            __syncthreads();
        }
    }

    for (int idx = t; idx < 1024; idx += 512) {
        int g = idx >> 8, n = idx & 255;
        float m = -3.9e38f;
#pragma unroll
        for (int k = 0; k < 32; ++k) m = fmaxf(m, bf2f(f2s[(size_t)(g * 32 + k) * 264 + n]));
        fgs[g * 256 + n] = f2bf(m);
    }
    __syncthreads();

    auto ldw3 = [&](int cb_, int ks_) -> bf16x8 {
        return *(const bf16x8*)(w3t + (size_t)(cb_ * 128 + w * 16 + lr) * 512 + ks_ * 32 + lq * 8);
    };
    auto ldw4 = [&](int cb_, int kl_, int nti_) -> bf16x8 {
        return *(const bf16x8*)(w4t + (size_t)(w * 48 + nti_ * 16 + lr) * 512 + cb_ * 128 + kl_ * 32 + lq * 8);
    };

    f32x4 acc4[3][8];
#pragma unroll
    for (int nti = 0; nti < 3; ++nti) {
        f32x4 bq = *(const f32x4*)(b4 + w * 48 + nti * 16 + lq * 4);
#pragma unroll
        for (int mt = 0; mt < 8; ++mt) acc4[nti][mt] = bq;
    }

    for (int cb = 0; cb < 4; ++cb) {
        bf16x8 wp[4];
#pragma unroll
        for (int kp = 0; kp < 4; ++kp) wp[kp] = ldw3(cb, kp);

        f32x4 accH = *(const f32x4*)(b3 + cb * 128 + w * 16 + lq * 4);
#pragma unroll
        for (int ks = 0; ks < 8; ++ks) {
            bf16x8 wf = wp[ks & 3];
            wp[ks & 3] = ldw3(cb, ks + 4);
            bf16x8 xfh = *(const bf16x8*)(fgs + (lr & 3) * 256 + ks * 32 + lq * 8);
            accH = __builtin_amdgcn_mfma_f32_16x16x32_bf16(wf, xfh, accH, 0, 0, 0);
        }
        f32x4 acc3[8];
#pragma unroll
        for (int mt = 0; mt < 8; ++mt) {
            const int gg = mt >> 1;
#pragma unroll
            for (int r = 0; r < 4; ++r)
                acc3[mt][r] = __shfl(accH[r], (lane & 48) | gg, 64);
        }
#pragma unroll
        for (int ks = 8; ks < 16; ++ks) {
            bf16x8 wf = wp[ks & 3];
            if (ks + 4 < 16) wp[ks & 3] = ldw3(cb, ks + 4);
#pragma unroll
            for (int mt = 0; mt < 8; ++mt) {
                bf16x8 xf = *(const bf16x8*)(f2s + (size_t)(mt * 16 + lr) * 264 + (ks - 8) * 32 + lq * 8);
                acc3[mt] = __builtin_amdgcn_mfma_f32_16x16x32_bf16(wf, xf, acc3[mt], 0, 0, 0);
            }
        }
        {
            const int nq = cb * 128 + w * 16 + lq * 4;
            f32x4 g2q = *(const f32x4*)(g2 + nq);
            f32x4 v2q = *(const f32x4*)(v2 + nq);
            f32x4 m2q = *(const f32x4*)(m2 + nq);
            f32x4 beq = *(const f32x4*)(be2 + nq);
            f32x4 sc, sh;
#pragma unroll
            for (int r = 0; r < 4; ++r) {
                sc[r] = g2q[r] * rsqrtf(v2q[r] + EPSF);
                sh[r] = beq[r] - m2q[r] * sc[r];
            }
#pragma unroll
            for (int mt = 0; mt < 8; ++mt) {
                bf16x4 p;
#pragma unroll
                for (int r = 0; r < 4; ++r)
                    p[r] = (short)f2bf(fmaxf(acc3[mt][r] * sc[r] + sh[r], 0.0f));
                *(bf16x4*)(f3c + (size_t)(mt * 16 + lr) * 136 + w * 16 + lq * 4) = p;
            }
        }
        bf16x8 w4a[3];
#pragma unroll
        for (int nti = 0; nti < 3; ++nti) w4a[nti] = ldw4(cb, 0, nti);
        __syncthreads();
        for (int kl = 0; kl < 4; ++kl) {
            bf16x8 w4n[3];
            if (kl < 3) {
#pragma unroll
                for (int nti = 0; nti < 3; ++nti) w4n[nti] = ldw4(cb, kl + 1, nti);
            }
            bf16x8 xf8[8];
#pragma unroll
            for (int mt = 0; mt < 8; ++mt)
                xf8[mt] = *(const bf16x8*)(f3c + (size_t)(mt * 16 + lr) * 136 + kl * 32 + lq * 8);
#pragma unroll
            for (int nti = 0; nti < 3; ++nti)
#pragma unroll
                for (int mt = 0; mt < 8; ++mt)
                    acc4[nti][mt] = __builtin_amdgcn_mfma_f32_16x16x32_bf16(w4a[nti], xf8[mt], acc4[nti][mt], 0, 0, 0);
            if (kl < 3) {
#pragma unroll
                for (int nti = 0; nti < 3; ++nti) w4a[nti] = w4n[nti];
            }
        }
        __syncthreads();
    }

#pragma unroll
    for (int nti = 0; nti < 3; ++nti) {
#pragma unroll
        for (int gg = 0; gg < 4; ++gg) {
            f32x4 vv;
#pragma unroll
            for (int r = 0; r < 4; ++r)
                vv[r] = fmaxf(acc4[nti][2 * gg][r], acc4[nti][2 * gg + 1][r]);
#pragma unroll
            for (int mask = 1; mask <= 8; mask <<= 1) {
#pragma unroll
                for (int r = 0; r < 4; ++r)
                    vv[r] = fmaxf(vv[r], __shfl_xor(vv[r], mask, 64));
            }
            if (lr == 0)
                *(f32x4*)(out + (size_t)(g0 + gg) * 384 + w * 48 + nti * 16 + lq * 4) = vv;
        }
    }
}

extern "C" void kernel_launch(void* const* d_in, const int* in_sizes, int n_in,
                              void* d_out, int out_size, void* d_ws, size_t ws_size,
                              hipStream_t stream) {
    const float* pcd = (const float*)d_in[0];
    const float* w1 = (const float*)d_in[2];
    const float* b1 = (const float*)d_in[3];
    const float* g1 = (const float*)d_in[4];
    const float* be1 = (const float*)d_in[5];
    const float* m1 = (const float*)d_in[6];
    const float* v1 = (const float*)d_in[7];
    const float* w2 = (const float*)d_in[8];
    const float* b2 = (const float*)d_in[9];
    const float* w3 = (const float*)d_in[10];
    const float* b3 = (const float*)d_in[11];
    const float* g2 = (const float*)d_in[12];
    const float* be2 = (const float*)d_in[13];
    const float* m2 = (const float*)d_in[14];
    const float* v2 = (const float*)d_in[15];
    const float* w4 = (const float*)d_in[16];
    const float* b4 = (const float*)d_in[17];
    float* out = (float*)d_out;

    char* ws = (char*)d_ws;
    int* cidx = (int*)ws;                                   // 8192 B
    float* xg = (float*)(ws + 8192);                        // 1,572,864 B
    unsigned short* w2t = (unsigned short*)(ws + 1581056);  // 65,536 B
    unsigned short* w3t = (unsigned short*)(ws + 1646592);  // 524,288 B
    unsigned short* w4t = (unsigned short*)(ws + 2170880);  // 393,216 B

    fps_prep_kernel<<<152, 1024, 0, stream>>>(pcd, cidx, w2, w3, w4, w2t, w3t, w4t);
    knn_kernel<<<2048, 64, 0, stream>>>(pcd, cidx, xg);
    mlp_mfma_kernel<<<512, 512, 0, stream>>>(xg, w1, b1, g1, be1, m1, v1,
                                             w2t, b2, w3t, b3, g2, be2, m2, v2,
                                             w4t, b4, out);
}

// Round 15
// 368.629 us; speedup vs baseline: 1.2049x; 1.0476x over previous
//
#include <hip/hip_runtime.h>
#include <hip/hip_bf16.h>
#include <math.h>

#define N_PTS 16384
#define NUM_G 64
#define GRP_K 32
#define EPSF 1e-5f

typedef short bf16x8 __attribute__((ext_vector_type(8)));
typedef short bf16x4 __attribute__((ext_vector_type(4)));
typedef float f32x4 __attribute__((ext_vector_type(4)));
typedef unsigned short u16x8 __attribute__((ext_vector_type(8)));

__device__ __forceinline__ unsigned short f2bf(float x) {
    unsigned int u = __builtin_bit_cast(unsigned int, x);
    u = (u + 0x7FFFu + ((u >> 16) & 1u)) >> 16;
    return (unsigned short)u;
}
__device__ __forceinline__ float bf2f(unsigned short h) {
    unsigned int u = ((unsigned int)h) << 16;
    return __builtin_bit_cast(float, u);
}

// ---------------- Fused Phase A: FPS v5 + weight prep (unchanged from R14) ----------------
__global__ __launch_bounds__(1024)
__attribute__((amdgpu_waves_per_eu(4, 4)))
void fps_prep_kernel(const float* __restrict__ pcd, int* __restrict__ cidx,
                     const float* __restrict__ w2, const float* __restrict__ w3,
                     const float* __restrict__ w4,
                     unsigned short* __restrict__ w2t,
                     unsigned short* __restrict__ w3t,
                     unsigned short* __restrict__ w4t) {
    __shared__ unsigned long long wk[2][16];
    __shared__ int clds[NUM_G];
    __shared__ unsigned short tl[64][72];

    const int tid = threadIdx.x;

    if (blockIdx.x >= 32) {
        if (tid < 256) {
            const int tile = blockIdx.x - 32;
            const float* src;
            unsigned short* dst;
            int K, N, kt, nt;
            if (tile < 8) {
                src = w2; dst = w2t; K = 128; N = 256;
                kt = tile >> 2; nt = tile & 3;
            } else if (tile < 72) {
                int t2 = tile - 8;
                src = w3; dst = w3t; K = 512; N = 512;
                kt = t2 >> 3; nt = t2 & 7;
            } else {
                int t2 = tile - 72;
                src = w4; dst = w4t; K = 512; N = 384;
                kt = t2 / 6; nt = t2 % 6;
            }
            const int k0 = kt * 64, n0 = nt * 64;
            const int c = tid & 63, r0 = tid >> 6;
#pragma unroll
            for (int i = 0; i < 16; ++i) {
                int r = 4 * i + r0;
                tl[r][c] = f2bf(src[(size_t)(k0 + r) * N + n0 + c]);
            }
            __syncthreads();
            const int n = tid >> 2;
            const int kc = (tid & 3) * 16;
            u16x8 v0, v1;
#pragma unroll
            for (int j = 0; j < 8; ++j) {
                v0[j] = tl[kc + j][n];
                v1[j] = tl[kc + 8 + j][n];
            }
            *(u16x8*)(dst + (size_t)(n0 + n) * K + k0 + kc) = v0;
            *(u16x8*)(dst + (size_t)(n0 + n) * K + k0 + kc + 8) = v1;
        } else {
            __syncthreads();
        }
        return;
    }

    const int b = blockIdx.x;
    const int lane = tid & 63, w = tid >> 6;
    const float* xb = pcd + (size_t)b * 6 * N_PTS;
    const float4* Xc = (const float4*)xb;
    const float4* Yc = (const float4*)(xb + N_PTS);
    const float4* Zc = (const float4*)(xb + 2 * N_PTS);

    float dist[16];
#pragma unroll
    for (int j = 0; j < 16; ++j) dist[j] = 1e10f;

    int far = 0;
    for (int it = 0; it < NUM_G; ++it) {
        int fu = __builtin_amdgcn_readfirstlane(far);
        float cx = xb[fu], cy = xb[N_PTS + fu], cz = xb[2 * N_PTS + fu];
        if (tid == 0) clds[it] = fu;

        float bv = -1.0f;
        int bj = 0;
#pragma unroll
        for (int jp = 0; jp < 4; ++jp) {
            float4 xq = Xc[tid * 4 + jp];
            float4 yq = Yc[tid * 4 + jp];
            float4 zq = Zc[tid * 4 + jp];
            float xa[4] = {xq.x, xq.y, xq.z, xq.w};
            float ya[4] = {yq.x, yq.y, yq.z, yq.w};
            float za[4] = {zq.x, zq.y, zq.z, zq.w};
#pragma unroll
            for (int u = 0; u < 4; ++u) {
                const int j = jp * 4 + u;
                float dx = __fsub_rn(xa[u], cx);
                float dy = __fsub_rn(ya[u], cy);
                float dz = __fsub_rn(za[u], cz);
                float d = __fadd_rn(__fadd_rn(__fmul_rn(dx, dx), __fmul_rn(dy, dy)),
                                    __fmul_rn(dz, dz));
                dist[j] = fminf(dist[j], d);
                if (dist[j] > bv) { bv = dist[j]; bj = j; }
            }
        }
        float vmax = bv;
#pragma unroll
        for (int m = 1; m < 64; m <<= 1) {
            float o = __shfl_xor(vmax, m, 64);
            vmax = o > vmax ? o : vmax;
        }
        unsigned long long mk = __ballot(bv == vmax);
        int fl = __ffsll((unsigned long long)mk) - 1;
        int bjw = __shfl(bj, fl, 64);
        int idx = (((w << 6) | fl) << 4) + bjw;
        unsigned long long key =
            ((unsigned long long)__float_as_uint(vmax) << 32) | (unsigned int)~idx;
        if (lane == 0) wk[it & 1][w] = key;
        __syncthreads();
        unsigned long long k2 = (lane < 16) ? wk[it & 1][lane] : 0ull;
#pragma unroll
        for (int m = 1; m < 16; m <<= 1) {
            unsigned long long o = __shfl_xor(k2, m, 64);
            k2 = o > k2 ? o : k2;
        }
        k2 = __shfl(k2, 0, 64);
        far = (int)(~(unsigned int)k2);
    }
    __syncthreads();
    if (tid < NUM_G) cidx[b * NUM_G + tid] = clds[tid];
}

// ---------------- Phase B: KNN v3 — lazy top-4 cache, one wave per group ----------------
// Each lane keeps a sorted top-4 of its 256 owned points. Extraction (exact,
// (d2,idx)-lex order): butterfly merge2 over each lane's best-2 remaining.
// A lane rescans only when its cache has <2 valid (needs >2 of its points
// consumed): expected ~2-6 rescans/group vs the old 32 — cuts shuffle traffic
// ~3x and the per-round dependency chain from 3 butterflies to 1.
__device__ __forceinline__ void merge2(unsigned long long& a1, unsigned long long& a2,
                                       unsigned long long o1, unsigned long long o2) {
    unsigned long long hi = a1 > o1 ? a1 : o1;
    a1 = a1 < o1 ? a1 : o1;
    unsigned long long lo2 = a2 < o2 ? a2 : o2;
    a2 = hi < lo2 ? hi : lo2;
}
// sorted ascending insert of v into (c0<=c1<=c2<=c3), keeping 4 smallest
__device__ __forceinline__ void ins4(unsigned long long& c0, unsigned long long& c1,
                                     unsigned long long& c2, unsigned long long& c3,
                                     unsigned long long v) {
    if (v < c3) {
        unsigned long long t3 = c2 > v ? c2 : v;
        unsigned long long t2 = c2 > v ? v : c2;
        unsigned long long u2 = c1 > t2 ? c1 : t2;
        unsigned long long u1 = c1 > t2 ? t2 : c1;
        unsigned long long s1 = c0 > u1 ? c0 : u1;
        unsigned long long s0 = c0 > u1 ? u1 : c0;
        c0 = s0; c1 = s1; c2 = u2; c3 = t3;
    }
}

__global__ __launch_bounds__(64)
__attribute__((amdgpu_waves_per_eu(4, 4)))
void knn_kernel(const float* __restrict__ pcd,
                const int* __restrict__ cidx,
                float* __restrict__ xout) {
    const int b = blockIdx.x & 31;       // XCD-locality swizzle
    const int g = blockIdx.x >> 5;
    const int bg_out = b * NUM_G + g;
    const int lane = threadIdx.x;
    const float* xb = pcd + (size_t)b * 6 * N_PTS;

    const int ci = cidx[bg_out];
    const float cx = xb[ci], cy = xb[N_PTS + ci], cz = xb[2 * N_PTS + ci];

    const float4* X4 = (const float4*)xb;
    const float4* Y4 = (const float4*)(xb + N_PTS);
    const float4* Z4 = (const float4*)(xb + 2 * N_PTS);

    // per-lane sorted top-4 cache of its 256 points p = j*256 + lane*4 + u
    unsigned long long c0 = ~0ull, c1 = ~0ull, c2 = ~0ull, c3 = ~0ull;
#pragma unroll 8
    for (int j = 0; j < 64; ++j) {
        float4 xv = X4[j * 64 + lane];
        float4 yv = Y4[j * 64 + lane];
        float4 zv = Z4[j * 64 + lane];
        float xs4[4] = {xv.x, xv.y, xv.z, xv.w};
        float ys4[4] = {yv.x, yv.y, yv.z, yv.w};
        float zs4[4] = {zv.x, zv.y, zv.z, zv.w};
        unsigned int p = (unsigned int)(j * 256 + lane * 4);
#pragma unroll
        for (int u = 0; u < 4; ++u) {
            float dx = __fsub_rn(cx, xs4[u]);
            float dy = __fsub_rn(cy, ys4[u]);
            float dz = __fsub_rn(cz, zs4[u]);
            float d = __fadd_rn(__fadd_rn(__fmul_rn(dx, dx), __fmul_rn(dy, dy)),
                                __fmul_rn(dz, dz));
            ins4(c0, c1, c2, c3, ((unsigned long long)__float_as_uint(d) << 32) | (p + u));
        }
    }
    int cnt = 4;

    unsigned long long rm0 = 0, rm1 = 0, rm2 = 0, rm3 = 0;
    __shared__ int knn_sh[GRP_K];

    for (int r = 0; r < 16; ++r) {
        // refill any lane whose cache dropped below 2 valid (rare)
        while (true) {
            unsigned long long need = __ballot(cnt < 2);
            if (need == 0ull) break;
            const int wl = __ffsll(need) - 1;
            unsigned long long m0 = __shfl(rm0, wl, 64);
            unsigned long long m1 = __shfl(rm1, wl, 64);
            unsigned long long m2 = __shfl(rm2, wl, 64);
            unsigned long long m3 = __shfl(rm3, wl, 64);
            const int wsel = lane >> 4;
            unsigned long long mw = wsel == 0 ? m0 : (wsel == 1 ? m1 : (wsel == 2 ? m2 : m3));
            // lane covers owner wl's 4 points at j=lane: p = lane*256 + wl*4 + u
            float4 xv = X4[lane * 64 + wl];
            float4 yv = Y4[lane * 64 + wl];
            float4 zv = Z4[lane * 64 + wl];
            float xs4[4] = {xv.x, xv.y, xv.z, xv.w};
            float ys4[4] = {yv.x, yv.y, yv.z, yv.w};
            float zs4[4] = {zv.x, zv.y, zv.z, zv.w};
            unsigned int p = (unsigned int)(lane * 256 + wl * 4);
            unsigned long long s0 = ~0ull, s1 = ~0ull, s2 = ~0ull, s3 = ~0ull;
#pragma unroll
            for (int u = 0; u < 4; ++u) {
                float dx = __fsub_rn(cx, xs4[u]);
                float dy = __fsub_rn(cy, ys4[u]);
                float dz = __fsub_rn(cz, zs4[u]);
                float d = __fadd_rn(__fadd_rn(__fmul_rn(dx, dx), __fmul_rn(dy, dy)),
                                    __fmul_rn(dz, dz));
                unsigned long long v =
                    ((unsigned long long)__float_as_uint(d) << 32) | (p + u);
                if ((mw >> (((lane & 15) << 2) | u)) & 1ull) v = ~0ull;
                ins4(s0, s1, s2, s3, v);
            }
            // butterfly merge of sorted quads -> global top-4 of remaining
#pragma unroll
            for (int m = 1; m < 64; m <<= 1) {
                unsigned long long o0 = __shfl_xor(s0, m, 64);
                unsigned long long o1 = __shfl_xor(s1, m, 64);
                unsigned long long o2 = __shfl_xor(s2, m, 64);
                unsigned long long o3 = __shfl_xor(s3, m, 64);
                ins4(s0, s1, s2, s3, o0);
                ins4(s0, s1, s2, s3, o1);
                ins4(s0, s1, s2, s3, o2);
                ins4(s0, s1, s2, s3, o3);
            }
            if (lane == wl) { c0 = s0; c1 = s1; c2 = s2; c3 = s3; cnt = 4; }
        }

        // exact global top-2 from each lane's best-2 remaining
        unsigned long long r1 = c0, r2 = c1;
#pragma unroll
        for (int m = 1; m < 64; m <<= 1) {
            unsigned long long o1 = __shfl_xor(r1, m, 64);
            unsigned long long o2 = __shfl_xor(r2, m, 64);
            merge2(r1, r2, o1, o2);
        }
        const int q1 = (int)(unsigned int)r1;
        const int q2 = (int)(unsigned int)r2;
        if (lane == 0) { knn_sh[2 * r] = q1; knn_sh[2 * r + 1] = q2; }

        // pops: owner's c0 == extracted key; shift cache, mark removed bit
        const int o1l = (q1 >> 2) & 63;
        if (lane == o1l) {
            const int sl = ((q1 >> 8) << 2) | (q1 & 3);
            unsigned long long bit = 1ull << (sl & 63);
            rm0 |= ((sl >> 6) == 0) ? bit : 0ull;
            rm1 |= ((sl >> 6) == 1) ? bit : 0ull;
            rm2 |= ((sl >> 6) == 2) ? bit : 0ull;
            rm3 |= ((sl >> 6) == 3) ? bit : 0ull;
            c0 = c1; c1 = c2; c2 = c3; c3 = ~0ull; --cnt;
        }
        const int o2l = (q2 >> 2) & 63;
        if (lane == o2l) {
            const int sl = ((q2 >> 8) << 2) | (q2 & 3);
            unsigned long long bit = 1ull << (sl & 63);
            rm0 |= ((sl >> 6) == 0) ? bit : 0ull;
            rm1 |= ((sl >> 6) == 1) ? bit : 0ull;
            rm2 |= ((sl >> 6) == 2) ? bit : 0ull;
            rm3 |= ((sl >> 6) == 3) ? bit : 0ull;
            c0 = c1; c1 = c2; c2 = c3; c3 = ~0ull; --cnt;
        }
    }
    __syncthreads();

    // gather 32 x 6, subtract center from xyz channels
#pragma unroll
    for (int t = 0; t < 3; ++t) {
        int i = lane + 64 * t;
        int k = i / 6, c = i % 6;
        int p = knn_sh[k];
        float val = xb[c * N_PTS + p];
        if (c == 0) val = __fsub_rn(val, cx);
        else if (c == 1) val = __fsub_rn(val, cy);
        else if (c == 2) val = __fsub_rn(val, cz);
        xout[(size_t)bg_out * 192 + i] = val;
    }
}

// ---------------- Phase C: M=128 mega-block MFMA MLP (v2, 512 thr — unchanged) ----------------
__global__ __launch_bounds__(512, 2) void mlp_mfma_kernel(
    const float* __restrict__ xin,
    const float* __restrict__ w1, const float* __restrict__ b1,
    const float* __restrict__ g1, const float* __restrict__ be1,
    const float* __restrict__ m1, const float* __restrict__ v1,
    const unsigned short* __restrict__ w2t, const float* __restrict__ b2,
    const unsigned short* __restrict__ w3t, const float* __restrict__ b3,
    const float* __restrict__ g2, const float* __restrict__ be2,
    const float* __restrict__ m2, const float* __restrict__ v2,
    const unsigned short* __restrict__ w4t, const float* __restrict__ b4,
    float* __restrict__ out) {
    const int g0 = blockIdx.x * 4;
    const int t = threadIdx.x;
    const int w = t >> 6;
    const int lane = t & 63;
    const int lr = lane & 15;
    const int lq = lane >> 4;

    __shared__ __align__(16) unsigned short f2s[128 * 264];
    __shared__ __align__(16) unsigned short ubuf[128 * 136];
    __shared__ __align__(16) unsigned short fgs[4 * 256];
    __shared__ float xs[4 * 192];

    unsigned short* f1s = ubuf;
    unsigned short* f3c = ubuf;

    for (int i = t; i < 768; i += 512) xs[i] = xin[(size_t)g0 * 192 + i];
    __syncthreads();

    {
        const int d = t & 127, rq = t >> 7;
        float wv[6];
#pragma unroll
        for (int c = 0; c < 6; ++c) wv[c] = w1[c * 128 + d];
        const float sc = g1[d] * rsqrtf(v1[d] + EPSF);
        const float sh = be1[d] - m1[d] * sc;
        const float bias = b1[d];

        for (int s = 0; s < 2; ++s) {
#pragma unroll
            for (int j = 0; j < 16; ++j) {
                const int rl = rq * 16 + j;
                const int gr = s * 64 + rl;
                const int g = gr >> 5, k = gr & 31;
                float acc = bias;
#pragma unroll
                for (int c = 0; c < 6; ++c) acc += xs[g * 192 + k * 6 + c] * wv[c];
                f1s[rl * 136 + d] = f2bf(fmaxf(acc * sc + sh, 0.0f));
            }
            __syncthreads();
            f32x4 acc[4][2];
#pragma unroll
            for (int nti = 0; nti < 2; ++nti) {
                f32x4 bq = *(const f32x4*)(b2 + w * 32 + nti * 16 + lq * 4);
#pragma unroll
                for (int mtl = 0; mtl < 4; ++mtl) acc[mtl][nti] = bq;
            }
#pragma unroll
            for (int ks = 0; ks < 4; ++ks) {
                bf16x8 xf[4], wf[2];
#pragma unroll
                for (int mtl = 0; mtl < 4; ++mtl)
                    xf[mtl] = *(const bf16x8*)(f1s + (mtl * 16 + lr) * 136 + ks * 32 + lq * 8);
#pragma unroll
                for (int nti = 0; nti < 2; ++nti)
                    wf[nti] = *(const bf16x8*)(w2t + (w * 32 + nti * 16 + lr) * 128 + ks * 32 + lq * 8);
#pragma unroll
                for (int mtl = 0; mtl < 4; ++mtl)
#pragma unroll
                    for (int nti = 0; nti < 2; ++nti)
                        acc[mtl][nti] = __builtin_amdgcn_mfma_f32_16x16x32_bf16(wf[nti], xf[mtl], acc[mtl][nti], 0, 0, 0);
            }
#pragma unroll
            for (int mtl = 0; mtl < 4; ++mtl)
#pragma unroll
                for (int nti = 0; nti < 2; ++nti) {
                    bf16x4 p;
#pragma unroll
                    for (int r = 0; r < 4; ++r) p[r] = (short)f2bf(acc[mtl][nti][r]);
                    *(bf16x4*)(f2s + (size_t)(s * 64 + mtl * 16 + lr) * 264 + w * 32 + nti * 16 + lq * 4) = p;
                }
            __syncthreads();
        }
    }

    for (int idx = t; idx < 1024; idx += 512) {
        int g = idx >> 8, n = idx & 255;
        float m = -3.9e38f;
#pragma unroll
        for (int k = 0; k < 32; ++k) m = fmaxf(m, bf2f(f2s[(size_t)(g * 32 + k) * 264 + n]));
        fgs[g * 256 + n] = f2bf(m);
    }
    __syncthreads();

    auto ldw3 = [&](int cb_, int ks_) -> bf16x8 {
        return *(const bf16x8*)(w3t + (size_t)(cb_ * 128 + w * 16 + lr) * 512 + ks_ * 32 + lq * 8);
    };
    auto ldw4 = [&](int cb_, int kl_, int nti_) -> bf16x8 {
        return *(const bf16x8*)(w4t + (size_t)(w * 48 + nti_ * 16 + lr) * 512 + cb_ * 128 + kl_ * 32 + lq * 8);
    };

    f32x4 acc4[3][8];
#pragma unroll
    for (int nti = 0; nti < 3; ++nti) {
        f32x4 bq = *(const f32x4*)(b4 + w * 48 + nti * 16 + lq * 4);
#pragma unroll
        for (int mt = 0; mt < 8; ++mt) acc4[nti][mt] = bq;
    }

    for (int cb = 0; cb < 4; ++cb) {
        bf16x8 wp[4];
#pragma unroll
        for (int kp = 0; kp < 4; ++kp) wp[kp] = ldw3(cb, kp);

        f32x4 accH = *(const f32x4*)(b3 + cb * 128 + w * 16 + lq * 4);
#pragma unroll
        for (int ks = 0; ks < 8; ++ks) {
            bf16x8 wf = wp[ks & 3];
            wp[ks & 3] = ldw3(cb, ks + 4);
            bf16x8 xfh = *(const bf16x8*)(fgs + (lr & 3) * 256 + ks * 32 + lq * 8);
            accH = __builtin_amdgcn_mfma_f32_16x16x32_bf16(wf, xfh, accH, 0, 0, 0);
        }
        f32x4 acc3[8];
#pragma unroll
        for (int mt = 0; mt < 8; ++mt) {
            const int gg = mt >> 1;
#pragma unroll
            for (int r = 0; r < 4; ++r)
                acc3[mt][r] = __shfl(accH[r], (lane & 48) | gg, 64);
        }
#pragma unroll
        for (int ks = 8; ks < 16; ++ks) {
            bf16x8 wf = wp[ks & 3];
            if (ks + 4 < 16) wp[ks & 3] = ldw3(cb, ks + 4);
#pragma unroll
            for (int mt = 0; mt < 8; ++mt) {
                bf16x8 xf = *(const bf16x8*)(f2s + (size_t)(mt * 16 + lr) * 264 + (ks - 8) * 32 + lq * 8);
                acc3[mt] = __builtin_amdgcn_mfma_f32_16x16x32_bf16(wf, xf, acc3[mt], 0, 0, 0);
            }
        }
        {
            const int nq = cb * 128 + w * 16 + lq * 4;
            f32x4 g2q = *(const f32x4*)(g2 + nq);
            f32x4 v2q = *(const f32x4*)(v2 + nq);
            f32x4 m2q = *(const f32x4*)(m2 + nq);
            f32x4 beq = *(const f32x4*)(be2 + nq);
            f32x4 sc, sh;
#pragma unroll
            for (int r = 0; r < 4; ++r) {
                sc[r] = g2q[r] * rsqrtf(v2q[r] + EPSF);
                sh[r] = beq[r] - m2q[r] * sc[r];
            }
#pragma unroll
            for (int mt = 0; mt < 8; ++mt) {
                bf16x4 p;
#pragma unroll
                for (int r = 0; r < 4; ++r)
                    p[r] = (short)f2bf(fmaxf(acc3[mt][r] * sc[r] + sh[r], 0.0f));
                *(bf16x4*)(f3c + (size_t)(mt * 16 + lr) * 136 + w * 16 + lq * 4) = p;
            }
        }
        bf16x8 w4a[3];
#pragma unroll
        for (int nti = 0; nti < 3; ++nti) w4a[nti] = ldw4(cb, 0, nti);
        __syncthreads();
        for (int kl = 0; kl < 4; ++kl) {
            bf16x8 w4n[3];
            if (kl < 3) {
#pragma unroll
                for (int nti = 0; nti < 3; ++nti) w4n[nti] = ldw4(cb, kl + 1, nti);
            }
            bf16x8 xf8[8];
#pragma unroll
            for (int mt = 0; mt < 8; ++mt)
                xf8[mt] = *(const bf16x8*)(f3c + (size_t)(mt * 16 + lr) * 136 + kl * 32 + lq * 8);
#pragma unroll
            for (int nti = 0; nti < 3; ++nti)
#pragma unroll
                for (int mt = 0; mt < 8; ++mt)
                    acc4[nti][mt] = __builtin_amdgcn_mfma_f32_16x16x32_bf16(w4a[nti], xf8[mt], acc4[nti][mt], 0, 0, 0);
            if (kl < 3) {
#pragma unroll
                for (int nti = 0; nti < 3; ++nti) w4a[nti] = w4n[nti];
            }
        }
        __syncthreads();
    }

#pragma unroll
    for (int nti = 0; nti < 3; ++nti) {
#pragma unroll
        for (int gg = 0; gg < 4; ++gg) {
            f32x4 vv;
#pragma unroll
            for (int r = 0; r < 4; ++r)
                vv[r] = fmaxf(acc4[nti][2 * gg][r], acc4[nti][2 * gg + 1][r]);
#pragma unroll
            for (int mask = 1; mask <= 8; mask <<= 1) {
#pragma unroll
                for (int r = 0; r < 4; ++r)
                    vv[r] = fmaxf(vv[r], __shfl_xor(vv[r], mask, 64));
            }
            if (lr == 0)
                *(f32x4*)(out + (size_t)(g0 + gg) * 384 + w * 48 + nti * 16 + lq * 4) = vv;
        }
    }
}

extern "C" void kernel_launch(void* const* d_in, const int* in_sizes, int n_in,
                              void* d_out, int out_size, void* d_ws, size_t ws_size,
                              hipStream_t stream) {
    const float* pcd = (const float*)d_in[0];
    const float* w1 = (const float*)d_in[2];
    const float* b1 = (const float*)d_in[3];
    const float* g1 = (const float*)d_in[4];
    const float* be1 = (const float*)d_in[5];
    const float* m1 = (const float*)d_in[6];
    const float* v1 = (const float*)d_in[7];
    const float* w2 = (const float*)d_in[8];
    const float* b2 = (const float*)d_in[9];
    const float* w3 = (const float*)d_in[10];
    const float* b3 = (const float*)d_in[11];
    const float* g2 = (const float*)d_in[12];
    const float* be2 = (const float*)d_in[13];
    const float* m2 = (const float*)d_in[14];
    const float* v2 = (const float*)d_in[15];
    const float* w4 = (const float*)d_in[16];
    const float* b4 = (const float*)d_in[17];
    float* out = (float*)d_out;

    char* ws = (char*)d_ws;
    int* cidx = (int*)ws;                                   // 8192 B
    float* xg = (float*)(ws + 8192);                        // 1,572,864 B
    unsigned short* w2t = (unsigned short*)(ws + 1581056);  // 65,536 B
    unsigned short* w3t = (unsigned short*)(ws + 1646592);  // 524,288 B
    unsigned short* w4t = (unsigned short*)(ws + 2170880);  // 393,216 B

    fps_prep_kernel<<<152, 1024, 0, stream>>>(pcd, cidx, w2, w3, w4, w2t, w3t, w4t);
    knn_kernel<<<2048, 64, 0, stream>>>(pcd, cidx, xg);
    mlp_mfma_kernel<<<512, 512, 0, stream>>>(xg, w1, b1, g1, be1, m1, v1,
                                             w2t, b2, w3t, b3, g2, be2, m2, v2,
                                             w4t, b4, out);
}